// Round 1
// baseline (3615.981 us; speedup 1.0000x reference)
//
#include <hip/hip_runtime.h>

typedef __bf16 bf16;
typedef __attribute__((ext_vector_type(8))) __bf16 bf16x8;
typedef __attribute__((ext_vector_type(4))) __bf16 bf16x4;
typedef __attribute__((ext_vector_type(4))) float f32x4;

#define NL 6
#define DIM 1024
#define NH 16
#define DH 64
#define TT 2048
#define BB 2
#define BT 4096
#define FFD 4096
#define NSLOT 4096
#define NV 32000

__device__ __forceinline__ void gld16(const void* g, void* l) {
  __builtin_amdgcn_global_load_lds(
      (const __attribute__((address_space(1))) void*)g,
      (__attribute__((address_space(3))) void*)l, 16, 0, 0);
}

// ---------------- conversion / transpose kernels ----------------

__global__ void cvt_bf16(const float* __restrict__ s, bf16* __restrict__ d, long n) {
  long i = ((long)blockIdx.x * 256 + threadIdx.x) * 4;
  if (i + 3 < n) {
    float4 v = *(const float4*)(s + i);
    bf16x4 o = {(bf16)v.x, (bf16)v.y, (bf16)v.z, (bf16)v.w};
    *(bf16x4*)(d + i) = o;
  }
}

// src fp32 (R x C) -> dst bf16 (C x R)
__global__ void transpose_cvt(const float* __restrict__ src, bf16* __restrict__ dst, int R, int C) {
  __shared__ float tile[32][33];
  int c0 = blockIdx.x * 32, r0 = blockIdx.y * 32;
  int tx = threadIdx.x, ty = threadIdx.y;  // block (32,8)
#pragma unroll
  for (int i = 0; i < 4; ++i)
    tile[ty + i * 8][tx] = src[(size_t)(r0 + ty + i * 8) * C + c0 + tx];
  __syncthreads();
#pragma unroll
  for (int i = 0; i < 4; ++i)
    dst[(size_t)(c0 + ty + i * 8) * R + r0 + tx] = (bf16)tile[tx][ty + i * 8];
}

// v [b*T+t][h*DH+dh] bf16 -> vT [(b*NH+h)*DH+dh][t] bf16
__global__ void transpose_v(const bf16* __restrict__ v, bf16* __restrict__ vT) {
  __shared__ bf16 tile[32][33];
  int t0 = blockIdx.x * 32, d0 = blockIdx.y * 32, bh = blockIdx.z;
  int b = bh >> 4, h = bh & 15;
  int tx = threadIdx.x, ty = threadIdx.y;
#pragma unroll
  for (int i = 0; i < 4; ++i)
    tile[ty + i * 8][tx] = v[(size_t)(b * TT + t0 + ty + i * 8) * DIM + h * DH + d0 + tx];
  __syncthreads();
#pragma unroll
  for (int i = 0; i < 4; ++i)
    vT[((size_t)bh * DH + d0 + ty + i * 8) * TT + t0 + tx] = tile[tx][ty + i * 8];
}

// ---------------- embedding + rope ----------------

__global__ void embed_rope(const int* __restrict__ ids, const float* __restrict__ emb,
                           float* __restrict__ xf, bf16* __restrict__ xb) {
  int bt = blockIdx.x;
  int t = bt & (TT - 1);
  int id = ids[bt];
  const float* row = emb + (size_t)id * DIM;
  for (int p = threadIdx.x; p < DIM / 2; p += 256) {
    float x1 = row[2 * p], x2 = row[2 * p + 1];
    // inv_freq = 10000^(-2p/D) = exp(-ln(10000) * p / 512)
    float inv = __expf(-9.210340371976184f * (float)p * (1.0f / 512.0f));
    float ang = (float)t * inv;
    float c = cosf(ang), s = sinf(ang);
    float o1 = x1 * c - x2 * s;
    float o2 = x1 * s + x2 * c;
    size_t base = (size_t)bt * DIM + 2 * p;
    xf[base] = o1; xf[base + 1] = o2;
    xb[base] = (bf16)o1; xb[base + 1] = (bf16)o2;
  }
}

// ---------------- GEMM: C = A(bf16,MxK) * Bt(bf16,NxK)^T ----------------
// 128x128 tile, BK=64, 4 waves (2x2), 16x16x32 mfma, global_load_lds staging.

enum { EP_BF16 = 0, EP_F32 = 1, EP_F32_BIAS = 2, EP_BF16_BIAS = 3, EP_SILU_MUL = 4 };

template <int EP>
__global__ __launch_bounds__(256, 2) void gemm_bt(
    const bf16* __restrict__ A, const bf16* __restrict__ Bt, void* __restrict__ Cp,
    const float* __restrict__ bias, const bf16* __restrict__ aux,
    int M, int N, int K) {
  __shared__ bf16 As[128 * 64];
  __shared__ bf16 Bs[128 * 64];
  const int tid = threadIdx.x;
  const int lane = tid & 63, wave = tid >> 6;
  const int m0 = blockIdx.y * 128, n0 = blockIdx.x * 128;
  const int wr = (wave >> 1) * 64, wc = (wave & 1) * 64;
  const int r16 = lane & 15, kseg = (lane >> 4) * 8;

  const int srow = tid >> 3;         // 0..31
  const int scol = (tid & 7) * 8;    // 0..56
  const bf16* aSrc = A + (size_t)(m0 + srow) * K + scol;
  const bf16* bSrc = Bt + (size_t)(n0 + srow) * K + scol;
  const int ldsOff = srow * 64 + scol;

  f32x4 acc[4][4] = {};

  for (int kt = 0; kt < K; kt += 64) {
#pragma unroll
    for (int r4 = 0; r4 < 4; ++r4) {
      gld16(aSrc + kt + (size_t)r4 * 32 * K, &As[ldsOff + r4 * 32 * 64]);
      gld16(bSrc + kt + (size_t)r4 * 32 * K, &Bs[ldsOff + r4 * 32 * 64]);
    }
    __syncthreads();
#pragma unroll
    for (int kk = 0; kk < 2; ++kk) {
      bf16x8 af[4], bw[4];
#pragma unroll
      for (int i = 0; i < 4; ++i)
        af[i] = *(const bf16x8*)&As[(wr + i * 16 + r16) * 64 + kk * 32 + kseg];
#pragma unroll
      for (int j = 0; j < 4; ++j)
        bw[j] = *(const bf16x8*)&Bs[(wc + j * 16 + r16) * 64 + kk * 32 + kseg];
#pragma unroll
      for (int i = 0; i < 4; ++i)
#pragma unroll
        for (int j = 0; j < 4; ++j)
          acc[i][j] = __builtin_amdgcn_mfma_f32_16x16x32_bf16(af[i], bw[j], acc[i][j], 0, 0, 0);
    }
    __syncthreads();
  }

#pragma unroll
  for (int i = 0; i < 4; ++i) {
#pragma unroll
    for (int j = 0; j < 4; ++j) {
#pragma unroll
      for (int q = 0; q < 4; ++q) {
        int m = m0 + wr + i * 16 + (lane >> 4) * 4 + q;
        int n = n0 + wc + j * 16 + r16;
        size_t idx = (size_t)m * N + n;
        float v = acc[i][j][q];
        if constexpr (EP == EP_F32) {
          ((float*)Cp)[idx] = v;
        } else if constexpr (EP == EP_F32_BIAS) {
          ((float*)Cp)[idx] = v + bias[n];
        } else if constexpr (EP == EP_BF16) {
          ((bf16*)Cp)[idx] = (bf16)v;
        } else if constexpr (EP == EP_BF16_BIAS) {
          ((bf16*)Cp)[idx] = (bf16)(v + bias[n]);
        } else {  // EP_SILU_MUL: out = bf16( silu(acc) * aux )
          float sg = v / (1.0f + __expf(-v));
          ((bf16*)Cp)[idx] = (bf16)(sg * (float)aux[idx]);
        }
      }
    }
  }
}

// ---------------- flash attention (non-causal) ----------------
// grid (T/64, H, B), 256 threads = 4 waves, each wave owns 16 q rows.
// Q,K layout: [b*T+t][h*DH+dh]; V pre-transposed: [(b*NH+h)*DH+dh][t]. O: [b*T+t][h*DH+dh].

__global__ __launch_bounds__(256, 2) void attn_flash(
    const bf16* __restrict__ Qp, const bf16* __restrict__ Kp,
    const bf16* __restrict__ Vt, bf16* __restrict__ Op) {
  __shared__ bf16 Ks[128 * 64];
  __shared__ bf16 Vs[64 * 128];
  __shared__ bf16 Ps[4][16 * 128];
  const int tid = threadIdx.x, lane = tid & 63, wave = tid >> 6;
  const int h = blockIdx.y, b = blockIdx.z;
  const int r16 = lane & 15, kseg = (lane >> 4) * 8;
  const int qrow = blockIdx.x * 64 + wave * 16 + r16;

  bf16x8 qa[2];
  {
    const bf16* qp = Qp + ((size_t)(b * TT + qrow)) * DIM + h * DH + kseg;
    qa[0] = *(const bf16x8*)qp;
    qa[1] = *(const bf16x8*)(qp + 32);
  }
  const bf16* kBase = Kp + ((size_t)b * TT) * DIM + h * DH;
  const bf16* vBase = Vt + ((size_t)(b * NH + h)) * DH * TT;

  const int skrow = tid >> 3, skcol = (tid & 7) * 8;    // K stage
  const int svrow = tid >> 4, svcol = (tid & 15) * 8;   // V stage

  float m_run[4] = {-1e30f, -1e30f, -1e30f, -1e30f};
  float l_run[4] = {0.f, 0.f, 0.f, 0.f};
  f32x4 oacc[4] = {};

  for (int kt = 0; kt < TT; kt += 128) {
#pragma unroll
    for (int r4 = 0; r4 < 4; ++r4) {
      gld16(kBase + (size_t)(kt + r4 * 32 + skrow) * DIM + skcol, &Ks[(r4 * 32 + skrow) * 64 + skcol]);
      gld16(vBase + (size_t)(r4 * 16 + svrow) * TT + kt + svcol, &Vs[(r4 * 16 + svrow) * 128 + svcol]);
    }
    __syncthreads();

    f32x4 s[8];
#pragma unroll
    for (int kg = 0; kg < 8; ++kg) {
      f32x4 z = {};
      bf16x8 kb0 = *(const bf16x8*)&Ks[(kg * 16 + r16) * 64 + kseg];
      bf16x8 kb1 = *(const bf16x8*)&Ks[(kg * 16 + r16) * 64 + 32 + kseg];
      z = __builtin_amdgcn_mfma_f32_16x16x32_bf16(qa[0], kb0, z, 0, 0, 0);
      z = __builtin_amdgcn_mfma_f32_16x16x32_bf16(qa[1], kb1, z, 0, 0, 0);
      s[kg] = z * 0.125f;  // DH^-0.5
    }
#pragma unroll
    for (int i = 0; i < 4; ++i) {
      float pm = s[0][i];
#pragma unroll
      for (int kg = 1; kg < 8; ++kg) pm = fmaxf(pm, s[kg][i]);
      pm = fmaxf(pm, __shfl_xor(pm, 1));
      pm = fmaxf(pm, __shfl_xor(pm, 2));
      pm = fmaxf(pm, __shfl_xor(pm, 4));
      pm = fmaxf(pm, __shfl_xor(pm, 8));
      float mnew = fmaxf(m_run[i], pm);
      float sc = __expf(m_run[i] - mnew);
      m_run[i] = mnew;
      l_run[i] *= sc;
#pragma unroll
      for (int n = 0; n < 4; ++n) oacc[n][i] *= sc;
#pragma unroll
      for (int kg = 0; kg < 8; ++kg) {
        float p = __expf(s[kg][i] - mnew);
        l_run[i] += p;
        Ps[wave][((lane >> 4) * 4 + i) * 128 + kg * 16 + r16] = (bf16)p;
      }
    }
#pragma unroll
    for (int ks = 0; ks < 4; ++ks) {
      bf16x8 pa = *(const bf16x8*)&Ps[wave][r16 * 128 + ks * 32 + kseg];
#pragma unroll
      for (int n = 0; n < 4; ++n) {
        bf16x8 vb = *(const bf16x8*)&Vs[(n * 16 + r16) * 128 + ks * 32 + kseg];
        oacc[n] = __builtin_amdgcn_mfma_f32_16x16x32_bf16(pa, vb, oacc[n], 0, 0, 0);
      }
    }
    __syncthreads();
  }

#pragma unroll
  for (int i = 0; i < 4; ++i) {
    float l = l_run[i];
    l += __shfl_xor(l, 1);
    l += __shfl_xor(l, 2);
    l += __shfl_xor(l, 4);
    l += __shfl_xor(l, 8);
    float inv = 1.0f / l;
    int trow = blockIdx.x * 64 + wave * 16 + (lane >> 4) * 4 + i;
    size_t base = ((size_t)b * TT + trow) * DIM + h * DH;
#pragma unroll
    for (int n = 0; n < 4; ++n)
      Op[base + n * 16 + r16] = (bf16)(oacc[n][i] * inv);
  }
}

// ---------------- residual + rmsnorm ----------------

__global__ __launch_bounds__(256) void resid_rms(
    const float* __restrict__ xin, const float* __restrict__ y, const float* __restrict__ wgt,
    float* __restrict__ xf_out, bf16* __restrict__ xb_out) {
  __shared__ float red[4];
  const int r = blockIdx.x, tid = threadIdx.x;
  const size_t base = (size_t)r * DIM + tid * 4;
  float4 v = *(const float4*)(xin + base);
  float4 u = *(const float4*)(y + base);
  v.x += u.x; v.y += u.y; v.z += u.z; v.w += u.w;
  float ss = v.x * v.x + v.y * v.y + v.z * v.z + v.w * v.w;
#pragma unroll
  for (int d = 1; d < 64; d <<= 1) ss += __shfl_xor(ss, d);
  if ((tid & 63) == 0) red[tid >> 6] = ss;
  __syncthreads();
  ss = red[0] + red[1] + red[2] + red[3];
  float sc = rsqrtf(ss * (1.0f / DIM) + 1e-8f);
  const float4 wv = *(const float4*)(wgt + tid * 4);
  float o0 = v.x * sc * wv.x, o1 = v.y * sc * wv.y, o2 = v.z * sc * wv.z, o3 = v.w * sc * wv.w;
  if (xf_out) {
    float4 ov = {o0, o1, o2, o3};
    *(float4*)(xf_out + base) = ov;
  }
  bf16x4 ob = {(bf16)o0, (bf16)o1, (bf16)o2, (bf16)o3};
  *(bf16x4*)(xb_out + base) = ob;
}

// ---------------- slot softmax rows (scale D^-0.5 = 1/32) ----------------

__global__ __launch_bounds__(256) void softmax_rows(const float* __restrict__ Sc, bf16* __restrict__ P) {
  __shared__ float red[4];
  const int r = blockIdx.x, tid = threadIdx.x;
  const float* row = Sc + (size_t)r * NSLOT;
  float4 v[4];
#pragma unroll
  for (int i = 0; i < 4; ++i) v[i] = *(const float4*)(row + tid * 4 + i * 1024);
  float mx = -1e30f;
#pragma unroll
  for (int i = 0; i < 4; ++i)
    mx = fmaxf(fmaxf(fmaxf(fmaxf(mx, v[i].x), v[i].y), v[i].z), v[i].w);
#pragma unroll
  for (int d = 1; d < 64; d <<= 1) mx = fmaxf(mx, __shfl_xor(mx, d));
  if ((tid & 63) == 0) red[tid >> 6] = mx;
  __syncthreads();
  mx = fmaxf(fmaxf(red[0], red[1]), fmaxf(red[2], red[3]));
  __syncthreads();
  float e[16];
  float sum = 0.f;
#pragma unroll
  for (int i = 0; i < 4; ++i) {
    e[i * 4 + 0] = __expf((v[i].x - mx) * 0.03125f);
    e[i * 4 + 1] = __expf((v[i].y - mx) * 0.03125f);
    e[i * 4 + 2] = __expf((v[i].z - mx) * 0.03125f);
    e[i * 4 + 3] = __expf((v[i].w - mx) * 0.03125f);
    sum += e[i * 4 + 0] + e[i * 4 + 1] + e[i * 4 + 2] + e[i * 4 + 3];
  }
#pragma unroll
  for (int d = 1; d < 64; d <<= 1) sum += __shfl_xor(sum, d);
  if ((tid & 63) == 0) red[tid >> 6] = sum;
  __syncthreads();
  sum = red[0] + red[1] + red[2] + red[3];
  float inv = 1.0f / sum;
#pragma unroll
  for (int i = 0; i < 4; ++i) {
    bf16x4 ob = {(bf16)(e[i * 4 + 0] * inv), (bf16)(e[i * 4 + 1] * inv),
                 (bf16)(e[i * 4 + 2] * inv), (bf16)(e[i * 4 + 3] * inv)};
    *(bf16x4*)(P + (size_t)r * NSLOT + tid * 4 + i * 1024) = ob;
  }
}

// ---------------- host orchestration ----------------

extern "C" void kernel_launch(void* const* d_in, const int* in_sizes, int n_in,
                              void* d_out, int out_size, void* d_ws, size_t ws_size,
                              hipStream_t stream) {
  (void)in_sizes; (void)n_in; (void)out_size;
  const int* ids = (const int*)d_in[0];
  const float* emb = (const float*)d_in[1];
  const float* Wq = (const float*)d_in[2];
  const float* Wk = (const float*)d_in[3];
  const float* Wv = (const float*)d_in[4];
  const float* Wo = (const float*)d_in[5];
  const float* bo = (const float*)d_in[6];
  const float* n1 = (const float*)d_in[7];
  const float* Wg = (const float*)d_in[8];
  const float* Wu = (const float*)d_in[9];
  const float* Wd = (const float*)d_in[10];
  const float* n2 = (const float*)d_in[11];
  const float* memp = (const float*)d_in[12];
  const float* Wsp = (const float*)d_in[13];
  const float* bsp = (const float*)d_in[14];
  const float* Wrp = (const float*)d_in[15];
  const float* brp = (const float*)d_in[16];
  const float* nout = (const float*)d_in[17];

  char* w = (char*)d_ws;
  auto alloc = [&](size_t bytes) -> void* {
    void* p = (void*)w;
    w += (bytes + 255) & ~(size_t)255;
    return p;
  };

  const size_t dd = (size_t)DIM * DIM;
  const size_t dff = (size_t)DIM * FFD;

  bf16* tok_b = (bf16*)alloc((size_t)NV * DIM * 2);
  bf16* mem_b = (bf16*)alloc((size_t)NSLOT * DIM * 2);
  bf16* memT  = (bf16*)alloc((size_t)NSLOT * DIM * 2);
  bf16* WspT  = (bf16*)alloc(dd * 2);
  bf16* WrpT  = (bf16*)alloc(dd * 2);
  float* xf   = (float*)alloc((size_t)BT * DIM * 4);
  bf16* xb    = (bf16*)alloc((size_t)BT * DIM * 2);
  float* yb   = (float*)alloc((size_t)BT * DIM * 4);
  bf16* WqT   = (bf16*)alloc(dd * 2);
  bf16* WkT   = (bf16*)alloc(dd * 2);
  bf16* WvT   = (bf16*)alloc(dd * 2);
  bf16* WoT   = (bf16*)alloc(dd * 2);
  bf16* WgT   = (bf16*)alloc(dff * 2);
  bf16* WuT   = (bf16*)alloc(dff * 2);
  bf16* WdT   = (bf16*)alloc(dff * 2);
  bf16* qt_   = (bf16*)alloc((size_t)BT * DIM * 2);
  bf16* kt_   = (bf16*)alloc((size_t)BT * DIM * 2);
  bf16* vt_   = (bf16*)alloc((size_t)BT * DIM * 2);
  bf16* vT_   = (bf16*)alloc((size_t)BT * DIM * 2);
  bf16* ot_   = (bf16*)alloc((size_t)BT * DIM * 2);
  bf16* qb    = (bf16*)alloc((size_t)BT * DIM * 2);
  bf16* rb    = (bf16*)alloc((size_t)BT * DIM * 2);
  bf16* hb    = (bf16*)alloc((size_t)BT * DIM * 2);

  // Overlay region: FF activations (Ub,Hb) during layers, slot scores/attn after.
  size_t used = (size_t)(w - (char*)d_ws);
  size_t region_bytes = (size_t)BT * NSLOT * 4 + (size_t)BT * NSLOT * 2;
  char* region;
  if (used + region_bytes <= ws_size) region = (char*)alloc(region_bytes);
  else region = (char*)d_out;  // d_out (524 MB fp32) only written at the very end
  bf16* Ub = (bf16*)region;
  bf16* Hb = (bf16*)(region + (size_t)BT * FFD * 2);
  float* scoresF = (float*)region;
  bf16* attnb = (bf16*)(region + (size_t)BT * NSLOT * 4);

  dim3 blkT(32, 8);

  cvt_bf16<<<NV * DIM / 1024, 256, 0, stream>>>(emb, tok_b, (long)NV * DIM);
  cvt_bf16<<<NSLOT * DIM / 1024, 256, 0, stream>>>(memp, mem_b, (long)NSLOT * DIM);
  transpose_cvt<<<dim3(DIM / 32, NSLOT / 32), blkT, 0, stream>>>(memp, memT, NSLOT, DIM);
  transpose_cvt<<<dim3(DIM / 32, DIM / 32), blkT, 0, stream>>>(Wsp, WspT, DIM, DIM);
  transpose_cvt<<<dim3(DIM / 32, DIM / 32), blkT, 0, stream>>>(Wrp, WrpT, DIM, DIM);
  embed_rope<<<BT, 256, 0, stream>>>(ids, emb, xf, xb);

  for (int l = 0; l < NL; ++l) {
    transpose_cvt<<<dim3(32, 32), blkT, 0, stream>>>(Wq + l * dd, WqT, DIM, DIM);
    transpose_cvt<<<dim3(32, 32), blkT, 0, stream>>>(Wk + l * dd, WkT, DIM, DIM);
    transpose_cvt<<<dim3(32, 32), blkT, 0, stream>>>(Wv + l * dd, WvT, DIM, DIM);
    transpose_cvt<<<dim3(32, 32), blkT, 0, stream>>>(Wo + l * dd, WoT, DIM, DIM);
    transpose_cvt<<<dim3(FFD / 32, DIM / 32), blkT, 0, stream>>>(Wg + l * dff, WgT, DIM, FFD);
    transpose_cvt<<<dim3(FFD / 32, DIM / 32), blkT, 0, stream>>>(Wu + l * dff, WuT, DIM, FFD);
    transpose_cvt<<<dim3(DIM / 32, FFD / 32), blkT, 0, stream>>>(Wd + l * dff, WdT, FFD, DIM);

    gemm_bt<EP_BF16><<<dim3(8, 32), 256, 0, stream>>>(xb, WqT, qt_, nullptr, nullptr, BT, DIM, DIM);
    gemm_bt<EP_BF16><<<dim3(8, 32), 256, 0, stream>>>(xb, WkT, kt_, nullptr, nullptr, BT, DIM, DIM);
    gemm_bt<EP_BF16><<<dim3(8, 32), 256, 0, stream>>>(xb, WvT, vt_, nullptr, nullptr, BT, DIM, DIM);
    transpose_v<<<dim3(TT / 32, DH / 32, BB * NH), blkT, 0, stream>>>(vt_, vT_);
    attn_flash<<<dim3(TT / 64, NH, BB), 256, 0, stream>>>(qt_, kt_, vT_, ot_);
    gemm_bt<EP_F32_BIAS><<<dim3(8, 32), 256, 0, stream>>>(ot_, WoT, yb, bo + l * DIM, nullptr, BT, DIM, DIM);
    resid_rms<<<BT, 256, 0, stream>>>(xf, yb, n1 + l * DIM, xf, xb);
    gemm_bt<EP_BF16><<<dim3(32, 32), 256, 0, stream>>>(xb, WuT, Ub, nullptr, nullptr, BT, FFD, DIM);
    gemm_bt<EP_SILU_MUL><<<dim3(32, 32), 256, 0, stream>>>(xb, WgT, Hb, nullptr, Ub, BT, FFD, DIM);
    gemm_bt<EP_F32><<<dim3(8, 32), 256, 0, stream>>>(Hb, WdT, yb, nullptr, nullptr, BT, DIM, FFD);
    resid_rms<<<BT, 256, 0, stream>>>(xf, yb, n2 + l * DIM, xf, xb);
  }

  gemm_bt<EP_BF16_BIAS><<<dim3(8, 32), 256, 0, stream>>>(xb, WspT, qb, bsp, nullptr, BT, DIM, DIM);
  gemm_bt<EP_F32><<<dim3(32, 32), 256, 0, stream>>>(qb, mem_b, scoresF, nullptr, nullptr, BT, NSLOT, DIM);
  softmax_rows<<<BT, 256, 0, stream>>>(scoresF, attnb);
  gemm_bt<EP_BF16><<<dim3(8, 32), 256, 0, stream>>>(attnb, memT, rb, nullptr, nullptr, BT, DIM, NSLOT);
  gemm_bt<EP_F32_BIAS><<<dim3(8, 32), 256, 0, stream>>>(rb, WrpT, yb, brp, nullptr, BT, DIM, DIM);
  resid_rms<<<BT, 256, 0, stream>>>(xf, yb, nout, nullptr, hb);
  gemm_bt<EP_F32><<<dim3(NV / 128, 32), 256, 0, stream>>>(hb, tok_b, (float*)d_out, nullptr, nullptr, BT, NV, DIM);
}

// Round 2
// 3136.285 us; speedup vs baseline: 1.1530x; 1.1530x over previous
//
#include <hip/hip_runtime.h>

typedef __bf16 bf16;
typedef __attribute__((ext_vector_type(8))) __bf16 bf16x8;
typedef __attribute__((ext_vector_type(4))) __bf16 bf16x4;
typedef __attribute__((ext_vector_type(4))) float f32x4;

#define NL 6
#define DIM 1024
#define NH 16
#define DH 64
#define TT 2048
#define BB 2
#define BT 4096
#define FFD 4096
#define NSLOT 4096
#define NV 32000

__device__ __forceinline__ void gld16(const void* g, void* l) {
  __builtin_amdgcn_global_load_lds(
      (const __attribute__((address_space(1))) void*)g,
      (__attribute__((address_space(3))) void*)l, 16, 0, 0);
}

// ---------------- conversion / transpose kernels ----------------

__global__ void cvt_bf16(const float* __restrict__ s, bf16* __restrict__ d, long n) {
  long i = ((long)blockIdx.x * 256 + threadIdx.x) * 4;
  if (i + 3 < n) {
    float4 v = *(const float4*)(s + i);
    bf16x4 o = {(bf16)v.x, (bf16)v.y, (bf16)v.z, (bf16)v.w};
    *(bf16x4*)(d + i) = o;
  }
}

// src fp32 (R x C) -> dst bf16 (C x R)
__global__ void transpose_cvt(const float* __restrict__ src, bf16* __restrict__ dst, int R, int C) {
  __shared__ float tile[32][33];
  int c0 = blockIdx.x * 32, r0 = blockIdx.y * 32;
  int tx = threadIdx.x, ty = threadIdx.y;  // block (32,8)
#pragma unroll
  for (int i = 0; i < 4; ++i)
    tile[ty + i * 8][tx] = src[(size_t)(r0 + ty + i * 8) * C + c0 + tx];
  __syncthreads();
#pragma unroll
  for (int i = 0; i < 4; ++i)
    dst[(size_t)(c0 + ty + i * 8) * R + r0 + tx] = (bf16)tile[tx][ty + i * 8];
}

// v [b*T+t][ldv stride, h*DH+dh] bf16 -> vT [(b*NH+h)*DH+dh][t] bf16
__global__ void transpose_v(const bf16* __restrict__ v, int ldv, bf16* __restrict__ vT) {
  __shared__ bf16 tile[32][33];
  int t0 = blockIdx.x * 32, d0 = blockIdx.y * 32, bh = blockIdx.z;
  int b = bh >> 4, h = bh & 15;
  int tx = threadIdx.x, ty = threadIdx.y;
#pragma unroll
  for (int i = 0; i < 4; ++i)
    tile[ty + i * 8][tx] = v[(size_t)(b * TT + t0 + ty + i * 8) * ldv + h * DH + d0 + tx];
  __syncthreads();
#pragma unroll
  for (int i = 0; i < 4; ++i)
    vT[((size_t)bh * DH + d0 + ty + i * 8) * TT + t0 + tx] = tile[tx][ty + i * 8];
}

// ---------------- embedding + rope ----------------

__global__ void embed_rope(const int* __restrict__ ids, const float* __restrict__ emb,
                           float* __restrict__ xf, bf16* __restrict__ xb) {
  int bt = blockIdx.x;
  int t = bt & (TT - 1);
  int id = ids[bt];
  const float* row = emb + (size_t)id * DIM;
  for (int p = threadIdx.x; p < DIM / 2; p += 256) {
    float x1 = row[2 * p], x2 = row[2 * p + 1];
    float inv = __expf(-9.210340371976184f * (float)p * (1.0f / 512.0f));
    float ang = (float)t * inv;
    float c = cosf(ang), s = sinf(ang);
    float o1 = x1 * c - x2 * s;
    float o2 = x1 * s + x2 * c;
    size_t base = (size_t)bt * DIM + 2 * p;
    xf[base] = o1; xf[base + 1] = o2;
    xb[base] = (bf16)o1; xb[base + 1] = (bf16)o2;
  }
}

// ---------------- GEMM: C = A(bf16,MxK) * Bt(bf16,NxK)^T ----------------
// BK=32 (64-B LDS rows -> conflict-free b128 frag reads), 4-buffer ring,
// staged 2 K-tiles ahead via global_load_lds, counted vmcnt(6), one raw
// s_barrier per K-tile, setprio around MFMA cluster, bijective XCD swizzle.

enum { EP_BF16 = 0, EP_F32 = 1, EP_F32_BIAS = 2, EP_BF16_BIAS = 3, EP_SILU_MUL = 4 };

template <int BM, int BN, int WMW, int WNW, int EP>
__global__ __launch_bounds__(WMW * WNW * 64, 2) void gemmk(
    const bf16* __restrict__ A, const bf16* __restrict__ Bt, void* __restrict__ Cp,
    const float* __restrict__ bias, const bf16* __restrict__ aux,
    int M, int N, int K) {
  constexpr int BK = 32;
  constexpr int NWAVE = WMW * WNW;
  constexpr int NTHR = NWAVE * 64;
  constexpr int MF = BM / (WMW * 16);
  constexpr int NF = BN / (WNW * 16);
  constexpr int AE = BM * BK;
  constexpr int BE = BN * BK;
  constexpr int RHALF = NTHR / 4;  // rows covered per load pass
  __shared__ bf16 sA[4][AE];
  __shared__ bf16 sB[4][BE];

  const int tid = threadIdx.x;
  const int lane = tid & 63;
  const int r16 = lane & 15, hi = lane >> 4;
  const int wave = tid >> 6;
  const int wm = wave / WNW, wn = wave % WNW;

  // bijective XCD swizzle (m204)
  const int nwg = gridDim.x;
  const int orig = blockIdx.x;
  const int qq = nwg >> 3, rr = nwg & 7;
  const int xcd = orig & 7, cidx = orig >> 3;
  const int wg = (xcd < rr ? xcd * (qq + 1) : rr * (qq + 1) + (xcd - rr) * qq) + cidx;
  const int gM = M / BM;
  const int m0 = (wg % gM) * BM;
  const int n0 = (wg / gM) * BN;

  const int srow = tid >> 2;
  const int scol = (tid & 3) * 8;
  const bf16* aS = A + (size_t)(m0 + srow) * K + scol;
  const bf16* bS = Bt + (size_t)(n0 + srow) * K + scol;
  const int dst0 = srow * BK + scol;  // == tid*8 (linear, matches gld_lds lane mapping)

  f32x4 acc[MF][NF] = {};
  const int NT = K / BK;

  // prologue: stage tiles 0 and 1 (A then B each)
  gld16(aS, &sA[0][dst0]);
  gld16(aS + (size_t)RHALF * K, &sA[0][dst0 + RHALF * BK]);
  gld16(bS, &sB[0][dst0]);
  gld16(bS + (size_t)RHALF * K, &sB[0][dst0 + RHALF * BK]);
  gld16(aS + BK, &sA[1][dst0]);
  gld16(aS + BK + (size_t)RHALF * K, &sA[1][dst0 + RHALF * BK]);
  gld16(bS + BK, &sB[1][dst0]);
  gld16(bS + BK + (size_t)RHALF * K, &sB[1][dst0 + RHALF * BK]);

  for (int t = 0; t < NT; ++t) {
    const int cb = t & 3;
    const int pb = (t + 2) & 3;
    const bool pre = (t + 2) < NT;
    if (pre) {
      gld16(aS + (size_t)(t + 2) * BK, &sA[pb][dst0]);
      gld16(aS + (size_t)(t + 2) * BK + (size_t)RHALF * K, &sA[pb][dst0 + RHALF * BK]);
    }
    if (pre)             asm volatile("s_waitcnt vmcnt(6)" ::: "memory");
    else if (t + 1 < NT) asm volatile("s_waitcnt vmcnt(4)" ::: "memory");
    else                 asm volatile("s_waitcnt vmcnt(0)" ::: "memory");
    __builtin_amdgcn_s_barrier();
    __builtin_amdgcn_sched_barrier(0);

    bf16x8 bf_[NF];
#pragma unroll
    for (int j = 0; j < NF; ++j)
      bf_[j] = *(const bf16x8*)&sB[cb][(wn * (NF * 16) + j * 16 + r16) * BK + hi * 8];
    if (pre) {
      gld16(bS + (size_t)(t + 2) * BK, &sB[pb][dst0]);
      gld16(bS + (size_t)(t + 2) * BK + (size_t)RHALF * K, &sB[pb][dst0 + RHALF * BK]);
    }
    bf16x8 af[MF];
#pragma unroll
    for (int i = 0; i < MF; ++i)
      af[i] = *(const bf16x8*)&sA[cb][(wm * (MF * 16) + i * 16 + r16) * BK + hi * 8];
    __builtin_amdgcn_s_setprio(1);
#pragma unroll
    for (int i = 0; i < MF; ++i)
#pragma unroll
      for (int j = 0; j < NF; ++j)
        acc[i][j] = __builtin_amdgcn_mfma_f32_16x16x32_bf16(af[i], bf_[j], acc[i][j], 0, 0, 0);
    __builtin_amdgcn_s_setprio(0);
  }

#pragma unroll
  for (int i = 0; i < MF; ++i) {
    const int m = m0 + wm * (MF * 16) + i * 16 + hi * 4;
#pragma unroll
    for (int j = 0; j < NF; ++j) {
      const int n = n0 + wn * (NF * 16) + j * 16 + r16;
#pragma unroll
      for (int q = 0; q < 4; ++q) {
        size_t idx = (size_t)(m + q) * N + n;
        float v = acc[i][j][q];
        if constexpr (EP == EP_F32) {
          ((float*)Cp)[idx] = v;
        } else if constexpr (EP == EP_F32_BIAS) {
          ((float*)Cp)[idx] = v + bias[n];
        } else if constexpr (EP == EP_BF16) {
          ((bf16*)Cp)[idx] = (bf16)v;
        } else if constexpr (EP == EP_BF16_BIAS) {
          ((bf16*)Cp)[idx] = (bf16)(v + bias[n]);
        } else {
          float sg = v / (1.0f + __expf(-v));
          ((bf16*)Cp)[idx] = (bf16)(sg * (float)aux[idx]);
        }
      }
    }
  }
}

// ---------------- flash attention (non-causal) ----------------
// grid (T/64, H, B), 256 threads = 4 waves, each wave owns 16 q rows.
// Q,K from fused qkv buffer (row stride ldk); V pre-transposed [(b*NH+h)*DH+dh][t].
// LDS tiles chunked into 32-col (64-B row) arrays: conflict-free MFMA feeds.

__global__ __launch_bounds__(256, 2) void attn_flash(
    const bf16* __restrict__ Qp, const bf16* __restrict__ Kp, int ldk,
    const bf16* __restrict__ Vt, bf16* __restrict__ Op) {
  __shared__ bf16 Ks[2][128 * 32];      // [dh-half][row 0..127][32]
  __shared__ bf16 Vs[4][64 * 32];       // [t-chunk][d 0..63][32]
  __shared__ bf16 Ps[4][4][16 * 32];    // [wave][t-chunk][qrow 0..15][32]
  const int tid = threadIdx.x, lane = tid & 63, wave = tid >> 6;
  const int h = blockIdx.y, b = blockIdx.z;
  const int r16 = lane & 15, hi = lane >> 4;
  const int qrow = blockIdx.x * 64 + wave * 16 + r16;

  bf16x8 qa[2];
  {
    const bf16* qp = Qp + (size_t)(b * TT + qrow) * ldk + h * DH + hi * 8;
    qa[0] = *(const bf16x8*)qp;
    qa[1] = *(const bf16x8*)(qp + 32);
  }
  const bf16* kBase = Kp + (size_t)(b * TT) * ldk + h * DH;
  const bf16* vBase = Vt + (size_t)(b * NH + h) * DH * TT;

  const int srow = tid >> 2, scol = (tid & 3) * 8;

  float m_run[4] = {-1e30f, -1e30f, -1e30f, -1e30f};
  float l_run[4] = {0.f, 0.f, 0.f, 0.f};
  f32x4 oacc[4] = {};

  for (int kt = 0; kt < TT; kt += 128) {
#pragma unroll
    for (int half = 0; half < 2; ++half) {
      gld16(kBase + (size_t)(kt + srow) * ldk + half * 32 + scol, &Ks[half][srow * 32 + scol]);
      gld16(kBase + (size_t)(kt + 64 + srow) * ldk + half * 32 + scol, &Ks[half][(64 + srow) * 32 + scol]);
    }
#pragma unroll
    for (int ks = 0; ks < 4; ++ks)
      gld16(vBase + (size_t)srow * TT + kt + ks * 32 + scol, &Vs[ks][srow * 32 + scol]);
    __syncthreads();

    f32x4 s[8];
#pragma unroll
    for (int kg = 0; kg < 8; ++kg) {
      f32x4 z = {};
      bf16x8 kb0 = *(const bf16x8*)&Ks[0][(kg * 16 + r16) * 32 + hi * 8];
      bf16x8 kb1 = *(const bf16x8*)&Ks[1][(kg * 16 + r16) * 32 + hi * 8];
      z = __builtin_amdgcn_mfma_f32_16x16x32_bf16(qa[0], kb0, z, 0, 0, 0);
      z = __builtin_amdgcn_mfma_f32_16x16x32_bf16(qa[1], kb1, z, 0, 0, 0);
      s[kg] = z * 0.125f;  // DH^-0.5
    }
#pragma unroll
    for (int i = 0; i < 4; ++i) {
      float pm = s[0][i];
#pragma unroll
      for (int kg = 1; kg < 8; ++kg) pm = fmaxf(pm, s[kg][i]);
      pm = fmaxf(pm, __shfl_xor(pm, 1));
      pm = fmaxf(pm, __shfl_xor(pm, 2));
      pm = fmaxf(pm, __shfl_xor(pm, 4));
      pm = fmaxf(pm, __shfl_xor(pm, 8));
      float mnew = fmaxf(m_run[i], pm);
      float sc = __expf(m_run[i] - mnew);
      m_run[i] = mnew;
      l_run[i] *= sc;
#pragma unroll
      for (int n = 0; n < 4; ++n) oacc[n][i] *= sc;
#pragma unroll
      for (int kg = 0; kg < 8; ++kg) {
        float p = __expf(s[kg][i] - mnew);
        l_run[i] += p;
        Ps[wave][kg >> 1][(hi * 4 + i) * 32 + (kg & 1) * 16 + r16] = (bf16)p;
      }
    }
#pragma unroll
    for (int ks = 0; ks < 4; ++ks) {
      bf16x8 pa = *(const bf16x8*)&Ps[wave][ks][r16 * 32 + hi * 8];
#pragma unroll
      for (int n = 0; n < 4; ++n) {
        bf16x8 vb = *(const bf16x8*)&Vs[ks][(n * 16 + r16) * 32 + hi * 8];
        oacc[n] = __builtin_amdgcn_mfma_f32_16x16x32_bf16(pa, vb, oacc[n], 0, 0, 0);
      }
    }
    __syncthreads();
  }

#pragma unroll
  for (int i = 0; i < 4; ++i) {
    float l = l_run[i];
    l += __shfl_xor(l, 1);
    l += __shfl_xor(l, 2);
    l += __shfl_xor(l, 4);
    l += __shfl_xor(l, 8);
    float inv = 1.0f / l;
    int trow = blockIdx.x * 64 + wave * 16 + hi * 4 + i;
    size_t base = ((size_t)b * TT + trow) * DIM + h * DH;
#pragma unroll
    for (int n = 0; n < 4; ++n)
      Op[base + n * 16 + r16] = (bf16)(oacc[n][i] * inv);
  }
}

// ---------------- residual + rmsnorm ----------------

__global__ __launch_bounds__(256) void resid_rms(
    const float* __restrict__ xin, const float* __restrict__ y, const float* __restrict__ wgt,
    float* __restrict__ xf_out, bf16* __restrict__ xb_out) {
  __shared__ float red[4];
  const int r = blockIdx.x, tid = threadIdx.x;
  const size_t base = (size_t)r * DIM + tid * 4;
  float4 v = *(const float4*)(xin + base);
  float4 u = *(const float4*)(y + base);
  v.x += u.x; v.y += u.y; v.z += u.z; v.w += u.w;
  float ss = v.x * v.x + v.y * v.y + v.z * v.z + v.w * v.w;
#pragma unroll
  for (int d = 1; d < 64; d <<= 1) ss += __shfl_xor(ss, d);
  if ((tid & 63) == 0) red[tid >> 6] = ss;
  __syncthreads();
  ss = red[0] + red[1] + red[2] + red[3];
  float sc = rsqrtf(ss * (1.0f / DIM) + 1e-8f);
  const float4 wv = *(const float4*)(wgt + tid * 4);
  float o0 = v.x * sc * wv.x, o1 = v.y * sc * wv.y, o2 = v.z * sc * wv.z, o3 = v.w * sc * wv.w;
  if (xf_out) {
    float4 ov = {o0, o1, o2, o3};
    *(float4*)(xf_out + base) = ov;
  }
  bf16x4 ob = {(bf16)o0, (bf16)o1, (bf16)o2, (bf16)o3};
  *(bf16x4*)(xb_out + base) = ob;
}

// ---------------- slot softmax rows (scale D^-0.5 = 1/32) ----------------

__global__ __launch_bounds__(256) void softmax_rows(const float* __restrict__ Sc, bf16* __restrict__ P) {
  __shared__ float red[4];
  const int r = blockIdx.x, tid = threadIdx.x;
  const float* row = Sc + (size_t)r * NSLOT;
  float4 v[4];
#pragma unroll
  for (int i = 0; i < 4; ++i) v[i] = *(const float4*)(row + tid * 4 + i * 1024);
  float mx = -1e30f;
#pragma unroll
  for (int i = 0; i < 4; ++i)
    mx = fmaxf(fmaxf(fmaxf(fmaxf(mx, v[i].x), v[i].y), v[i].z), v[i].w);
#pragma unroll
  for (int d = 1; d < 64; d <<= 1) mx = fmaxf(mx, __shfl_xor(mx, d));
  if ((tid & 63) == 0) red[tid >> 6] = mx;
  __syncthreads();
  mx = fmaxf(fmaxf(red[0], red[1]), fmaxf(red[2], red[3]));
  __syncthreads();
  float e[16];
  float sum = 0.f;
#pragma unroll
  for (int i = 0; i < 4; ++i) {
    e[i * 4 + 0] = __expf((v[i].x - mx) * 0.03125f);
    e[i * 4 + 1] = __expf((v[i].y - mx) * 0.03125f);
    e[i * 4 + 2] = __expf((v[i].z - mx) * 0.03125f);
    e[i * 4 + 3] = __expf((v[i].w - mx) * 0.03125f);
    sum += e[i * 4 + 0] + e[i * 4 + 1] + e[i * 4 + 2] + e[i * 4 + 3];
  }
#pragma unroll
  for (int d = 1; d < 64; d <<= 1) sum += __shfl_xor(sum, d);
  if ((tid & 63) == 0) red[tid >> 6] = sum;
  __syncthreads();
  sum = red[0] + red[1] + red[2] + red[3];
  float inv = 1.0f / sum;
#pragma unroll
  for (int i = 0; i < 4; ++i) {
    bf16x4 ob = {(bf16)(e[i * 4 + 0] * inv), (bf16)(e[i * 4 + 1] * inv),
                 (bf16)(e[i * 4 + 2] * inv), (bf16)(e[i * 4 + 3] * inv)};
    *(bf16x4*)(P + (size_t)r * NSLOT + tid * 4 + i * 1024) = ob;
  }
}

// ---------------- host orchestration ----------------

extern "C" void kernel_launch(void* const* d_in, const int* in_sizes, int n_in,
                              void* d_out, int out_size, void* d_ws, size_t ws_size,
                              hipStream_t stream) {
  (void)in_sizes; (void)n_in; (void)out_size;
  const int* ids = (const int*)d_in[0];
  const float* emb = (const float*)d_in[1];
  const float* Wq = (const float*)d_in[2];
  const float* Wk = (const float*)d_in[3];
  const float* Wv = (const float*)d_in[4];
  const float* Wo = (const float*)d_in[5];
  const float* bo = (const float*)d_in[6];
  const float* n1 = (const float*)d_in[7];
  const float* Wg = (const float*)d_in[8];
  const float* Wu = (const float*)d_in[9];
  const float* Wd = (const float*)d_in[10];
  const float* n2 = (const float*)d_in[11];
  const float* memp = (const float*)d_in[12];
  const float* Wsp = (const float*)d_in[13];
  const float* bsp = (const float*)d_in[14];
  const float* Wrp = (const float*)d_in[15];
  const float* brp = (const float*)d_in[16];
  const float* nout = (const float*)d_in[17];

  char* w = (char*)d_ws;
  auto alloc = [&](size_t bytes) -> void* {
    void* p = (void*)w;
    w += (bytes + 255) & ~(size_t)255;
    return p;
  };

  const size_t dd = (size_t)DIM * DIM;
  const size_t dff = (size_t)DIM * FFD;

  bf16* tok_b = (bf16*)alloc((size_t)NV * DIM * 2);
  bf16* mem_b = (bf16*)alloc((size_t)NSLOT * DIM * 2);
  bf16* memT  = (bf16*)alloc((size_t)NSLOT * DIM * 2);
  bf16* WspT  = (bf16*)alloc(dd * 2);
  bf16* WrpT  = (bf16*)alloc(dd * 2);
  float* xf   = (float*)alloc((size_t)BT * DIM * 4);
  bf16* xb    = (bf16*)alloc((size_t)BT * DIM * 2);
  float* yb   = (float*)alloc((size_t)BT * DIM * 4);
  bf16* W3T   = (bf16*)alloc(3 * dd * 2);   // [WqT | WkT | WvT] rows
  bf16* WoT   = (bf16*)alloc(dd * 2);
  bf16* WgT   = (bf16*)alloc(dff * 2);
  bf16* WuT   = (bf16*)alloc(dff * 2);
  bf16* WdT   = (bf16*)alloc(dff * 2);
  bf16* qkv   = (bf16*)alloc((size_t)BT * 3 * DIM * 2);
  bf16* vT_   = (bf16*)alloc((size_t)BT * DIM * 2);
  bf16* ot_   = (bf16*)alloc((size_t)BT * DIM * 2);
  bf16* qb    = (bf16*)alloc((size_t)BT * DIM * 2);
  bf16* rb    = (bf16*)alloc((size_t)BT * DIM * 2);
  bf16* hb    = (bf16*)alloc((size_t)BT * DIM * 2);

  // Overlay region: FF activations (Ub,Hb) during layers, slot scores/attn after.
  size_t used = (size_t)(w - (char*)d_ws);
  size_t region_bytes = (size_t)BT * NSLOT * 4 + (size_t)BT * NSLOT * 2;
  char* region;
  if (used + region_bytes <= ws_size) region = (char*)alloc(region_bytes);
  else region = (char*)d_out;  // d_out (524 MB fp32) only written at the very end
  bf16* Ub = (bf16*)region;
  bf16* Hb = (bf16*)(region + (size_t)BT * FFD * 2);
  float* scoresF = (float*)region;
  bf16* attnb = (bf16*)(region + (size_t)BT * NSLOT * 4);

  dim3 blkT(32, 8);

  cvt_bf16<<<NV * DIM / 1024, 256, 0, stream>>>(emb, tok_b, (long)NV * DIM);
  cvt_bf16<<<NSLOT * DIM / 1024, 256, 0, stream>>>(memp, mem_b, (long)NSLOT * DIM);
  transpose_cvt<<<dim3(DIM / 32, NSLOT / 32), blkT, 0, stream>>>(memp, memT, NSLOT, DIM);
  transpose_cvt<<<dim3(DIM / 32, DIM / 32), blkT, 0, stream>>>(Wsp, WspT, DIM, DIM);
  transpose_cvt<<<dim3(DIM / 32, DIM / 32), blkT, 0, stream>>>(Wrp, WrpT, DIM, DIM);
  embed_rope<<<BT, 256, 0, stream>>>(ids, emb, xf, xb);

  for (int l = 0; l < NL; ++l) {
    transpose_cvt<<<dim3(32, 32), blkT, 0, stream>>>(Wq + l * dd, W3T, DIM, DIM);
    transpose_cvt<<<dim3(32, 32), blkT, 0, stream>>>(Wk + l * dd, W3T + dd, DIM, DIM);
    transpose_cvt<<<dim3(32, 32), blkT, 0, stream>>>(Wv + l * dd, W3T + 2 * dd, DIM, DIM);
    transpose_cvt<<<dim3(32, 32), blkT, 0, stream>>>(Wo + l * dd, WoT, DIM, DIM);
    transpose_cvt<<<dim3(FFD / 32, DIM / 32), blkT, 0, stream>>>(Wg + l * dff, WgT, DIM, FFD);
    transpose_cvt<<<dim3(FFD / 32, DIM / 32), blkT, 0, stream>>>(Wu + l * dff, WuT, DIM, FFD);
    transpose_cvt<<<dim3(DIM / 32, FFD / 32), blkT, 0, stream>>>(Wd + l * dff, WdT, FFD, DIM);

    // fused QKV: [BT][3072]
    gemmk<256, 256, 2, 4, EP_BF16><<<dim3(16 * 12), 512, 0, stream>>>(
        xb, W3T, qkv, nullptr, nullptr, BT, 3 * DIM, DIM);
    transpose_v<<<dim3(TT / 32, DH / 32, BB * NH), blkT, 0, stream>>>(qkv + 2 * DIM, 3 * DIM, vT_);
    attn_flash<<<dim3(TT / 64, NH, BB), 256, 0, stream>>>(qkv, qkv + DIM, 3 * DIM, vT_, ot_);
    gemmk<128, 128, 2, 2, EP_F32_BIAS><<<dim3(8 * 32), 256, 0, stream>>>(
        ot_, WoT, yb, bo + l * DIM, nullptr, BT, DIM, DIM);
    resid_rms<<<BT, 256, 0, stream>>>(xf, yb, n1 + l * DIM, xf, xb);
    gemmk<256, 256, 2, 4, EP_BF16><<<dim3(16 * 16), 512, 0, stream>>>(
        xb, WuT, Ub, nullptr, nullptr, BT, FFD, DIM);
    gemmk<256, 256, 2, 4, EP_SILU_MUL><<<dim3(16 * 16), 512, 0, stream>>>(
        xb, WgT, Hb, nullptr, Ub, BT, FFD, DIM);
    gemmk<128, 128, 2, 2, EP_F32><<<dim3(8 * 32), 256, 0, stream>>>(
        Hb, WdT, yb, nullptr, nullptr, BT, DIM, FFD);
    resid_rms<<<BT, 256, 0, stream>>>(xf, yb, n2 + l * DIM, xf, xb);
  }

  gemmk<128, 128, 2, 2, EP_BF16_BIAS><<<dim3(8 * 32), 256, 0, stream>>>(
      xb, WspT, qb, bsp, nullptr, BT, DIM, DIM);
  gemmk<256, 256, 2, 4, EP_F32><<<dim3(16 * 16), 512, 0, stream>>>(
      qb, mem_b, scoresF, nullptr, nullptr, BT, NSLOT, DIM);
  softmax_rows<<<BT, 256, 0, stream>>>(scoresF, attnb);
  gemmk<128, 128, 2, 2, EP_BF16><<<dim3(8 * 32), 256, 0, stream>>>(
      attnb, memT, rb, nullptr, nullptr, BT, DIM, NSLOT);
  gemmk<128, 128, 2, 2, EP_F32_BIAS><<<dim3(8 * 32), 256, 0, stream>>>(
      rb, WrpT, yb, brp, nullptr, BT, DIM, DIM);
  resid_rms<<<BT, 256, 0, stream>>>(xf, yb, nout, nullptr, hb);
  gemmk<256, 256, 2, 4, EP_F32><<<dim3(16 * 125), 512, 0, stream>>>(
      hb, tok_b, (float*)d_out, nullptr, nullptr, BT, NV, DIM);
}

// Round 3
// 3071.768 us; speedup vs baseline: 1.1772x; 1.0210x over previous
//
#include <hip/hip_runtime.h>

typedef __bf16 bf16;
typedef __attribute__((ext_vector_type(8))) __bf16 bf16x8;
typedef __attribute__((ext_vector_type(4))) __bf16 bf16x4;
typedef __attribute__((ext_vector_type(4))) float f32x4;

#define NL 6
#define DIM 1024
#define NH 16
#define DH 64
#define TT 2048
#define BB 2
#define BT 4096
#define FFD 4096
#define NSLOT 4096
#define NV 32000

__device__ __forceinline__ void gld16(const void* g, void* l) {
  __builtin_amdgcn_global_load_lds(
      (const __attribute__((address_space(1))) void*)g,
      (__attribute__((address_space(3))) void*)l, 16, 0, 0);
}

// ---------------- conversion / transpose kernels ----------------

__global__ void cvt_bf16(const float* __restrict__ s, bf16* __restrict__ d, long n) {
  long i = ((long)blockIdx.x * 256 + threadIdx.x) * 4;
  if (i + 3 < n) {
    float4 v = *(const float4*)(s + i);
    bf16x4 o = {(bf16)v.x, (bf16)v.y, (bf16)v.z, (bf16)v.w};
    *(bf16x4*)(d + i) = o;
  }
}

// src fp32 (R x C) -> dst bf16 (C x R)
__global__ void transpose_cvt(const float* __restrict__ src, bf16* __restrict__ dst, int R, int C) {
  __shared__ float tile[32][33];
  int c0 = blockIdx.x * 32, r0 = blockIdx.y * 32;
  int tx = threadIdx.x, ty = threadIdx.y;  // block (32,8)
#pragma unroll
  for (int i = 0; i < 4; ++i)
    tile[ty + i * 8][tx] = src[(size_t)(r0 + ty + i * 8) * C + c0 + tx];
  __syncthreads();
#pragma unroll
  for (int i = 0; i < 4; ++i)
    dst[(size_t)(c0 + ty + i * 8) * R + r0 + tx] = (bf16)tile[tx][ty + i * 8];
}

// v [b*T+t][ldv stride, h*DH+dh] bf16 -> vT [(b*NH+h)*DH+dh][t] bf16
__global__ void transpose_v(const bf16* __restrict__ v, int ldv, bf16* __restrict__ vT) {
  __shared__ bf16 tile[32][33];
  int t0 = blockIdx.x * 32, d0 = blockIdx.y * 32, bh = blockIdx.z;
  int b = bh >> 4, h = bh & 15;
  int tx = threadIdx.x, ty = threadIdx.y;
#pragma unroll
  for (int i = 0; i < 4; ++i)
    tile[ty + i * 8][tx] = v[(size_t)(b * TT + t0 + ty + i * 8) * ldv + h * DH + d0 + tx];
  __syncthreads();
#pragma unroll
  for (int i = 0; i < 4; ++i)
    vT[((size_t)bh * DH + d0 + ty + i * 8) * TT + t0 + tx] = tile[tx][ty + i * 8];
}

// ---------------- embedding + rope ----------------

__global__ void embed_rope(const int* __restrict__ ids, const float* __restrict__ emb,
                           float* __restrict__ xf, bf16* __restrict__ xb) {
  int bt = blockIdx.x;
  int t = bt & (TT - 1);
  int id = ids[bt];
  const float* row = emb + (size_t)id * DIM;
  for (int p = threadIdx.x; p < DIM / 2; p += 256) {
    float x1 = row[2 * p], x2 = row[2 * p + 1];
    float inv = __expf(-9.210340371976184f * (float)p * (1.0f / 512.0f));
    float ang = (float)t * inv;
    float c = cosf(ang), s = sinf(ang);
    float o1 = x1 * c - x2 * s;
    float o2 = x1 * s + x2 * c;
    size_t base = (size_t)bt * DIM + 2 * p;
    xf[base] = o1; xf[base + 1] = o2;
    xb[base] = (bf16)o1; xb[base + 1] = (bf16)o2;
  }
}

// ---------------- GEMM: C = A(bf16,MxK) * Bt(bf16,NxK)^T ----------------
// BK=32, 4-buffer ring staged 2 K-tiles ahead (counted vmcnt(6)), one raw
// s_barrier per K-tile, setprio around MFMA, bijective XCD swizzle.
// T2: XOR chunk-swizzle, both-sides involution: staging pre-swizzles the
// GLOBAL column (LDS dest stays linear per gld_lds rules); frag reads apply
// the same XOR -> every 8-lane b128 group covers all 32 banks exactly once.

enum { EP_BF16 = 0, EP_F32 = 1, EP_F32_BIAS = 2, EP_BF16_BIAS = 3, EP_SILU_MUL = 4 };

template <int BM, int BN, int WMW, int WNW, int EP>
__global__ __launch_bounds__(WMW * WNW * 64, 2) void gemmk(
    const bf16* __restrict__ A, const bf16* __restrict__ Bt, void* __restrict__ Cp,
    const float* __restrict__ bias, const bf16* __restrict__ aux,
    int M, int N, int K) {
  constexpr int BK = 32;
  constexpr int NWAVE = WMW * WNW;
  constexpr int NTHR = NWAVE * 64;
  constexpr int MF = BM / (WMW * 16);
  constexpr int NF = BN / (WNW * 16);
  constexpr int AE = BM * BK;
  constexpr int BE = BN * BK;
  constexpr int RHALF = NTHR / 4;  // rows covered per load pass
  __shared__ bf16 sA[4][AE];
  __shared__ bf16 sB[4][BE];

  const int tid = threadIdx.x;
  const int lane = tid & 63;
  const int r16 = lane & 15, hi = lane >> 4;
  const int wave = tid >> 6;
  const int wm = wave / WNW, wn = wave % WNW;

  // bijective XCD swizzle (m204)
  const int nwg = gridDim.x;
  const int orig = blockIdx.x;
  const int qq = nwg >> 3, rr = nwg & 7;
  const int xcd = orig & 7, cidx = orig >> 3;
  const int wg = (xcd < rr ? xcd * (qq + 1) : rr * (qq + 1) + (xcd - rr) * qq) + cidx;
  const int gM = M / BM;
  const int m0 = (wg % gM) * BM;
  const int n0 = (wg / gM) * BN;

  const int srow = tid >> 2;
  const int ccol = tid & 3;
  const int skey = (srow >> 1) & 3;          // swizzle key for this staged row
  const int gcol = ((ccol ^ skey)) * 8;      // pre-swizzled GLOBAL column (elems)
  const bf16* aS = A + (size_t)(m0 + srow) * K + gcol;
  const bf16* bS = Bt + (size_t)(n0 + srow) * K + gcol;
  const int dst0 = srow * BK + ccol * 8;     // linear LDS dest (== tid*8 elems)

  const int rkey = (r16 >> 1) & 3;           // read-side swizzle key
  const int rchunk = (hi ^ rkey) * 8;        // swizzled chunk offset (elems)

  f32x4 acc[MF][NF] = {};
  const int NT = K / BK;

  // prologue: stage tiles 0 and 1
  gld16(aS, &sA[0][dst0]);
  gld16(aS + (size_t)RHALF * K, &sA[0][dst0 + RHALF * BK]);
  gld16(bS, &sB[0][dst0]);
  gld16(bS + (size_t)RHALF * K, &sB[0][dst0 + RHALF * BK]);
  gld16(aS + BK, &sA[1][dst0]);
  gld16(aS + BK + (size_t)RHALF * K, &sA[1][dst0 + RHALF * BK]);
  gld16(bS + BK, &sB[1][dst0]);
  gld16(bS + BK + (size_t)RHALF * K, &sB[1][dst0 + RHALF * BK]);

  for (int t = 0; t < NT; ++t) {
    const int cb = t & 3;
    const int pb = (t + 2) & 3;
    const bool pre = (t + 2) < NT;
    if (pre) {
      gld16(aS + (size_t)(t + 2) * BK, &sA[pb][dst0]);
      gld16(aS + (size_t)(t + 2) * BK + (size_t)RHALF * K, &sA[pb][dst0 + RHALF * BK]);
    }
    if (pre)             asm volatile("s_waitcnt vmcnt(6)" ::: "memory");
    else if (t + 1 < NT) asm volatile("s_waitcnt vmcnt(4)" ::: "memory");
    else                 asm volatile("s_waitcnt vmcnt(0)" ::: "memory");
    __builtin_amdgcn_s_barrier();
    __builtin_amdgcn_sched_barrier(0);

    bf16x8 bf_[NF];
#pragma unroll
    for (int j = 0; j < NF; ++j)
      bf_[j] = *(const bf16x8*)&sB[cb][(wn * (NF * 16) + j * 16 + r16) * BK + rchunk];
    if (pre) {
      gld16(bS + (size_t)(t + 2) * BK, &sB[pb][dst0]);
      gld16(bS + (size_t)(t + 2) * BK + (size_t)RHALF * K, &sB[pb][dst0 + RHALF * BK]);
    }
    bf16x8 af[MF];
#pragma unroll
    for (int i = 0; i < MF; ++i)
      af[i] = *(const bf16x8*)&sA[cb][(wm * (MF * 16) + i * 16 + r16) * BK + rchunk];
    __builtin_amdgcn_s_setprio(1);
#pragma unroll
    for (int i = 0; i < MF; ++i)
#pragma unroll
      for (int j = 0; j < NF; ++j)
        acc[i][j] = __builtin_amdgcn_mfma_f32_16x16x32_bf16(af[i], bf_[j], acc[i][j], 0, 0, 0);
    __builtin_amdgcn_s_setprio(0);
  }

#pragma unroll
  for (int i = 0; i < MF; ++i) {
    const int m = m0 + wm * (MF * 16) + i * 16 + hi * 4;
#pragma unroll
    for (int j = 0; j < NF; ++j) {
      const int n = n0 + wn * (NF * 16) + j * 16 + r16;
#pragma unroll
      for (int q = 0; q < 4; ++q) {
        size_t idx = (size_t)(m + q) * N + n;
        float v = acc[i][j][q];
        if constexpr (EP == EP_F32) {
          ((float*)Cp)[idx] = v;
        } else if constexpr (EP == EP_F32_BIAS) {
          ((float*)Cp)[idx] = v + bias[n];
        } else if constexpr (EP == EP_BF16) {
          ((bf16*)Cp)[idx] = (bf16)v;
        } else if constexpr (EP == EP_BF16_BIAS) {
          ((bf16*)Cp)[idx] = (bf16)(v + bias[n]);
        } else {
          float sg = v / (1.0f + __expf(-v));
          ((bf16*)Cp)[idx] = (bf16)(sg * (float)aux[idx]);
        }
      }
    }
  }
}

// ---------------- flash attention (non-causal) ----------------
// grid (T/64, H, B), 256 threads = 4 waves, each wave owns 16 q rows.
// Ks/Vs: gld_lds-staged with source-side XOR swizzle + matching read swizzle.
// Ps: stride-40 rows (20-dword) -> 8-lane b128 groups start at disjoint banks.

__global__ __launch_bounds__(256, 2) void attn_flash(
    const bf16* __restrict__ Qp, const bf16* __restrict__ Kp, int ldk,
    const bf16* __restrict__ Vt, bf16* __restrict__ Op) {
  __shared__ bf16 Ks[2][128 * 32];      // [dh-half][row 0..127][32]
  __shared__ bf16 Vs[4][64 * 32];       // [t-chunk][d 0..63][32]
  __shared__ bf16 Ps[4][4][16 * 40];    // [wave][t-chunk][qrow 0..15][pad 40]
  const int tid = threadIdx.x, lane = tid & 63, wave = tid >> 6;
  const int h = blockIdx.y, b = blockIdx.z;
  const int r16 = lane & 15, hi = lane >> 4;
  const int qrow = blockIdx.x * 64 + wave * 16 + r16;

  bf16x8 qa[2];
  {
    const bf16* qp = Qp + (size_t)(b * TT + qrow) * ldk + h * DH + hi * 8;
    qa[0] = *(const bf16x8*)qp;
    qa[1] = *(const bf16x8*)(qp + 32);
  }
  const bf16* kBase = Kp + (size_t)(b * TT) * ldk + h * DH;
  const bf16* vBase = Vt + (size_t)(b * NH + h) * DH * TT;

  const int srow = tid >> 2, ccol = tid & 3;
  const int skey = (srow >> 1) & 3;
  const int scolS = (ccol ^ skey) * 8;   // swizzled source col (elems)
  const int dstc = ccol * 8;             // linear LDS dest col
  const int rkey = (r16 >> 1) & 3;
  const int rchunk = (hi ^ rkey) * 8;

  float m_run[4] = {-1e30f, -1e30f, -1e30f, -1e30f};
  float l_run[4] = {0.f, 0.f, 0.f, 0.f};
  f32x4 oacc[4] = {};

  for (int kt = 0; kt < TT; kt += 128) {
#pragma unroll
    for (int half = 0; half < 2; ++half) {
      gld16(kBase + (size_t)(kt + srow) * ldk + half * 32 + scolS, &Ks[half][srow * 32 + dstc]);
      gld16(kBase + (size_t)(kt + 64 + srow) * ldk + half * 32 + scolS, &Ks[half][(64 + srow) * 32 + dstc]);
    }
#pragma unroll
    for (int ks = 0; ks < 4; ++ks)
      gld16(vBase + (size_t)srow * TT + kt + ks * 32 + scolS, &Vs[ks][srow * 32 + dstc]);
    __syncthreads();

    f32x4 s[8];
#pragma unroll
    for (int kg = 0; kg < 8; ++kg) {
      f32x4 z = {};
      bf16x8 kb0 = *(const bf16x8*)&Ks[0][(kg * 16 + r16) * 32 + rchunk];
      bf16x8 kb1 = *(const bf16x8*)&Ks[1][(kg * 16 + r16) * 32 + rchunk];
      z = __builtin_amdgcn_mfma_f32_16x16x32_bf16(qa[0], kb0, z, 0, 0, 0);
      z = __builtin_amdgcn_mfma_f32_16x16x32_bf16(qa[1], kb1, z, 0, 0, 0);
      s[kg] = z * 0.125f;  // DH^-0.5
    }
#pragma unroll
    for (int i = 0; i < 4; ++i) {
      float pm = s[0][i];
#pragma unroll
      for (int kg = 1; kg < 8; ++kg) pm = fmaxf(pm, s[kg][i]);
      pm = fmaxf(pm, __shfl_xor(pm, 1));
      pm = fmaxf(pm, __shfl_xor(pm, 2));
      pm = fmaxf(pm, __shfl_xor(pm, 4));
      pm = fmaxf(pm, __shfl_xor(pm, 8));
      float mnew = fmaxf(m_run[i], pm);
      float sc = __expf(m_run[i] - mnew);
      m_run[i] = mnew;
      l_run[i] *= sc;
#pragma unroll
      for (int n = 0; n < 4; ++n) oacc[n][i] *= sc;
#pragma unroll
      for (int kg = 0; kg < 8; ++kg) {
        float p = __expf(s[kg][i] - mnew);
        l_run[i] += p;
        Ps[wave][kg >> 1][(hi * 4 + i) * 40 + (kg & 1) * 16 + r16] = (bf16)p;
      }
    }
#pragma unroll
    for (int ks = 0; ks < 4; ++ks) {
      bf16x8 pa = *(const bf16x8*)&Ps[wave][ks][r16 * 40 + hi * 8];
#pragma unroll
      for (int n = 0; n < 4; ++n) {
        bf16x8 vb = *(const bf16x8*)&Vs[ks][(n * 16 + r16) * 32 + rchunk];
        oacc[n] = __builtin_amdgcn_mfma_f32_16x16x32_bf16(pa, vb, oacc[n], 0, 0, 0);
      }
    }
    __syncthreads();
  }

#pragma unroll
  for (int i = 0; i < 4; ++i) {
    float l = l_run[i];
    l += __shfl_xor(l, 1);
    l += __shfl_xor(l, 2);
    l += __shfl_xor(l, 4);
    l += __shfl_xor(l, 8);
    float inv = 1.0f / l;
    int trow = blockIdx.x * 64 + wave * 16 + hi * 4 + i;
    size_t base = ((size_t)b * TT + trow) * DIM + h * DH;
#pragma unroll
    for (int n = 0; n < 4; ++n)
      Op[base + n * 16 + r16] = (bf16)(oacc[n][i] * inv);
  }
}

// ---------------- residual + rmsnorm ----------------

__global__ __launch_bounds__(256) void resid_rms(
    const float* __restrict__ xin, const float* __restrict__ y, const float* __restrict__ wgt,
    float* __restrict__ xf_out, bf16* __restrict__ xb_out) {
  __shared__ float red[4];
  const int r = blockIdx.x, tid = threadIdx.x;
  const size_t base = (size_t)r * DIM + tid * 4;
  float4 v = *(const float4*)(xin + base);
  float4 u = *(const float4*)(y + base);
  v.x += u.x; v.y += u.y; v.z += u.z; v.w += u.w;
  float ss = v.x * v.x + v.y * v.y + v.z * v.z + v.w * v.w;
#pragma unroll
  for (int d = 1; d < 64; d <<= 1) ss += __shfl_xor(ss, d);
  if ((tid & 63) == 0) red[tid >> 6] = ss;
  __syncthreads();
  ss = red[0] + red[1] + red[2] + red[3];
  float sc = rsqrtf(ss * (1.0f / DIM) + 1e-8f);
  const float4 wv = *(const float4*)(wgt + tid * 4);
  float o0 = v.x * sc * wv.x, o1 = v.y * sc * wv.y, o2 = v.z * sc * wv.z, o3 = v.w * sc * wv.w;
  if (xf_out) {
    float4 ov = {o0, o1, o2, o3};
    *(float4*)(xf_out + base) = ov;
  }
  bf16x4 ob = {(bf16)o0, (bf16)o1, (bf16)o2, (bf16)o3};
  *(bf16x4*)(xb_out + base) = ob;
}

// ---------------- slot softmax rows (scale D^-0.5 = 1/32) ----------------

__global__ __launch_bounds__(256) void softmax_rows(const float* __restrict__ Sc, bf16* __restrict__ P) {
  __shared__ float red[4];
  const int r = blockIdx.x, tid = threadIdx.x;
  const float* row = Sc + (size_t)r * NSLOT;
  float4 v[4];
#pragma unroll
  for (int i = 0; i < 4; ++i) v[i] = *(const float4*)(row + tid * 4 + i * 1024);
  float mx = -1e30f;
#pragma unroll
  for (int i = 0; i < 4; ++i)
    mx = fmaxf(fmaxf(fmaxf(fmaxf(mx, v[i].x), v[i].y), v[i].z), v[i].w);
#pragma unroll
  for (int d = 1; d < 64; d <<= 1) mx = fmaxf(mx, __shfl_xor(mx, d));
  if ((tid & 63) == 0) red[tid >> 6] = mx;
  __syncthreads();
  mx = fmaxf(fmaxf(red[0], red[1]), fmaxf(red[2], red[3]));
  __syncthreads();
  float e[16];
  float sum = 0.f;
#pragma unroll
  for (int i = 0; i < 4; ++i) {
    e[i * 4 + 0] = __expf((v[i].x - mx) * 0.03125f);
    e[i * 4 + 1] = __expf((v[i].y - mx) * 0.03125f);
    e[i * 4 + 2] = __expf((v[i].z - mx) * 0.03125f);
    e[i * 4 + 3] = __expf((v[i].w - mx) * 0.03125f);
    sum += e[i * 4 + 0] + e[i * 4 + 1] + e[i * 4 + 2] + e[i * 4 + 3];
  }
#pragma unroll
  for (int d = 1; d < 64; d <<= 1) sum += __shfl_xor(sum, d);
  if ((tid & 63) == 0) red[tid >> 6] = sum;
  __syncthreads();
  sum = red[0] + red[1] + red[2] + red[3];
  float inv = 1.0f / sum;
#pragma unroll
  for (int i = 0; i < 4; ++i) {
    bf16x4 ob = {(bf16)(e[i * 4 + 0] * inv), (bf16)(e[i * 4 + 1] * inv),
                 (bf16)(e[i * 4 + 2] * inv), (bf16)(e[i * 4 + 3] * inv)};
    *(bf16x4*)(P + (size_t)r * NSLOT + tid * 4 + i * 1024) = ob;
  }
}

// ---------------- host orchestration ----------------

extern "C" void kernel_launch(void* const* d_in, const int* in_sizes, int n_in,
                              void* d_out, int out_size, void* d_ws, size_t ws_size,
                              hipStream_t stream) {
  (void)in_sizes; (void)n_in; (void)out_size;
  const int* ids = (const int*)d_in[0];
  const float* emb = (const float*)d_in[1];
  const float* Wq = (const float*)d_in[2];
  const float* Wk = (const float*)d_in[3];
  const float* Wv = (const float*)d_in[4];
  const float* Wo = (const float*)d_in[5];
  const float* bo = (const float*)d_in[6];
  const float* n1 = (const float*)d_in[7];
  const float* Wg = (const float*)d_in[8];
  const float* Wu = (const float*)d_in[9];
  const float* Wd = (const float*)d_in[10];
  const float* n2 = (const float*)d_in[11];
  const float* memp = (const float*)d_in[12];
  const float* Wsp = (const float*)d_in[13];
  const float* bsp = (const float*)d_in[14];
  const float* Wrp = (const float*)d_in[15];
  const float* brp = (const float*)d_in[16];
  const float* nout = (const float*)d_in[17];

  char* w = (char*)d_ws;
  auto alloc = [&](size_t bytes) -> void* {
    void* p = (void*)w;
    w += (bytes + 255) & ~(size_t)255;
    return p;
  };

  const size_t dd = (size_t)DIM * DIM;
  const size_t dff = (size_t)DIM * FFD;

  bf16* tok_b = (bf16*)alloc((size_t)NV * DIM * 2);
  bf16* mem_b = (bf16*)alloc((size_t)NSLOT * DIM * 2);
  bf16* memT  = (bf16*)alloc((size_t)NSLOT * DIM * 2);
  bf16* WspT  = (bf16*)alloc(dd * 2);
  bf16* WrpT  = (bf16*)alloc(dd * 2);
  float* xf   = (float*)alloc((size_t)BT * DIM * 4);
  bf16* xb    = (bf16*)alloc((size_t)BT * DIM * 2);
  float* yb   = (float*)alloc((size_t)BT * DIM * 4);
  bf16* W3T   = (bf16*)alloc(3 * dd * 2);   // [WqT | WkT | WvT] rows
  bf16* WoT   = (bf16*)alloc(dd * 2);
  bf16* WgT   = (bf16*)alloc(dff * 2);
  bf16* WuT   = (bf16*)alloc(dff * 2);
  bf16* WdT   = (bf16*)alloc(dff * 2);
  bf16* qkv   = (bf16*)alloc((size_t)BT * 3 * DIM * 2);
  bf16* vT_   = (bf16*)alloc((size_t)BT * DIM * 2);
  bf16* ot_   = (bf16*)alloc((size_t)BT * DIM * 2);
  bf16* qb    = (bf16*)alloc((size_t)BT * DIM * 2);
  bf16* rb    = (bf16*)alloc((size_t)BT * DIM * 2);
  bf16* hb    = (bf16*)alloc((size_t)BT * DIM * 2);

  // Overlay region: FF activations (Ub,Hb) during layers, slot scores/attn after.
  size_t used = (size_t)(w - (char*)d_ws);
  size_t region_bytes = (size_t)BT * NSLOT * 4 + (size_t)BT * NSLOT * 2;
  char* region;
  if (used + region_bytes <= ws_size) region = (char*)alloc(region_bytes);
  else region = (char*)d_out;  // d_out (524 MB fp32) only written at the very end
  bf16* Ub = (bf16*)region;
  bf16* Hb = (bf16*)(region + (size_t)BT * FFD * 2);
  float* scoresF = (float*)region;
  bf16* attnb = (bf16*)(region + (size_t)BT * NSLOT * 4);

  dim3 blkT(32, 8);

  cvt_bf16<<<NV * DIM / 1024, 256, 0, stream>>>(emb, tok_b, (long)NV * DIM);
  cvt_bf16<<<NSLOT * DIM / 1024, 256, 0, stream>>>(memp, mem_b, (long)NSLOT * DIM);
  transpose_cvt<<<dim3(DIM / 32, NSLOT / 32), blkT, 0, stream>>>(memp, memT, NSLOT, DIM);
  transpose_cvt<<<dim3(DIM / 32, DIM / 32), blkT, 0, stream>>>(Wsp, WspT, DIM, DIM);
  transpose_cvt<<<dim3(DIM / 32, DIM / 32), blkT, 0, stream>>>(Wrp, WrpT, DIM, DIM);
  embed_rope<<<BT, 256, 0, stream>>>(ids, emb, xf, xb);

  for (int l = 0; l < NL; ++l) {
    transpose_cvt<<<dim3(32, 32), blkT, 0, stream>>>(Wq + l * dd, W3T, DIM, DIM);
    transpose_cvt<<<dim3(32, 32), blkT, 0, stream>>>(Wk + l * dd, W3T + dd, DIM, DIM);
    transpose_cvt<<<dim3(32, 32), blkT, 0, stream>>>(Wv + l * dd, W3T + 2 * dd, DIM, DIM);
    transpose_cvt<<<dim3(32, 32), blkT, 0, stream>>>(Wo + l * dd, WoT, DIM, DIM);
    transpose_cvt<<<dim3(FFD / 32, DIM / 32), blkT, 0, stream>>>(Wg + l * dff, WgT, DIM, FFD);
    transpose_cvt<<<dim3(FFD / 32, DIM / 32), blkT, 0, stream>>>(Wu + l * dff, WuT, DIM, FFD);
    transpose_cvt<<<dim3(DIM / 32, FFD / 32), blkT, 0, stream>>>(Wd + l * dff, WdT, FFD, DIM);

    // fused QKV: [BT][3072]  (128^2 tiles -> 768 blocks, full CU fill)
    gemmk<128, 128, 2, 2, EP_BF16><<<dim3(32 * 24), 256, 0, stream>>>(
        xb, W3T, qkv, nullptr, nullptr, BT, 3 * DIM, DIM);
    transpose_v<<<dim3(TT / 32, DH / 32, BB * NH), blkT, 0, stream>>>(qkv + 2 * DIM, 3 * DIM, vT_);
    attn_flash<<<dim3(TT / 64, NH, BB), 256, 0, stream>>>(qkv, qkv + DIM, 3 * DIM, vT_, ot_);
    gemmk<128, 128, 2, 2, EP_F32_BIAS><<<dim3(8 * 32), 256, 0, stream>>>(
        ot_, WoT, yb, bo + l * DIM, nullptr, BT, DIM, DIM);
    resid_rms<<<BT, 256, 0, stream>>>(xf, yb, n1 + l * DIM, xf, xb);
    gemmk<256, 256, 2, 4, EP_BF16><<<dim3(16 * 16), 512, 0, stream>>>(
        xb, WuT, Ub, nullptr, nullptr, BT, FFD, DIM);
    gemmk<256, 256, 2, 4, EP_SILU_MUL><<<dim3(16 * 16), 512, 0, stream>>>(
        xb, WgT, Hb, nullptr, Ub, BT, FFD, DIM);
    gemmk<128, 128, 2, 2, EP_F32><<<dim3(8 * 32), 256, 0, stream>>>(
        Hb, WdT, yb, nullptr, nullptr, BT, DIM, FFD);
    resid_rms<<<BT, 256, 0, stream>>>(xf, yb, n2 + l * DIM, xf, xb);
  }

  gemmk<128, 128, 2, 2, EP_BF16_BIAS><<<dim3(8 * 32), 256, 0, stream>>>(
      xb, WspT, qb, bsp, nullptr, BT, DIM, DIM);
  gemmk<256, 256, 2, 4, EP_F32><<<dim3(16 * 16), 512, 0, stream>>>(
      qb, mem_b, scoresF, nullptr, nullptr, BT, NSLOT, DIM);
  softmax_rows<<<BT, 256, 0, stream>>>(scoresF, attnb);
  gemmk<128, 128, 2, 2, EP_BF16><<<dim3(8 * 32), 256, 0, stream>>>(
      attnb, memT, rb, nullptr, nullptr, BT, DIM, NSLOT);
  gemmk<128, 128, 2, 2, EP_F32_BIAS><<<dim3(8 * 32), 256, 0, stream>>>(
      rb, WrpT, yb, brp, nullptr, BT, DIM, DIM);
  resid_rms<<<BT, 256, 0, stream>>>(xf, yb, nout, nullptr, hb);
  gemmk<256, 256, 2, 4, EP_F32><<<dim3(16 * 125), 512, 0, stream>>>(
      hb, tok_b, (float*)d_out, nullptr, nullptr, BT, NV, DIM);
}

// Round 4
// 2918.494 us; speedup vs baseline: 1.2390x; 1.0525x over previous
//
#include <hip/hip_runtime.h>

typedef __bf16 bf16;
typedef __attribute__((ext_vector_type(8))) __bf16 bf16x8;
typedef __attribute__((ext_vector_type(4))) __bf16 bf16x4;
typedef __attribute__((ext_vector_type(4))) float f32x4;

#define NL 6
#define DIM 1024
#define NH 16
#define DH 64
#define TT 2048
#define BB 2
#define BT 4096
#define FFD 4096
#define NSLOT 4096
#define NV 32000

__device__ __forceinline__ void gld16(const void* g, void* l) {
  __builtin_amdgcn_global_load_lds(
      (const __attribute__((address_space(1))) void*)g,
      (__attribute__((address_space(3))) void*)l, 16, 0, 0);
}

// ---------------- conversion / transpose kernels ----------------

__global__ void cvt_bf16(const float* __restrict__ s, bf16* __restrict__ d, long n) {
  long i = ((long)blockIdx.x * 256 + threadIdx.x) * 4;
  if (i + 3 < n) {
    float4 v = *(const float4*)(s + i);
    bf16x4 o = {(bf16)v.x, (bf16)v.y, (bf16)v.z, (bf16)v.w};
    *(bf16x4*)(d + i) = o;
  }
}

// src fp32 (R x C) -> dst bf16 (C x R)
__global__ void transpose_cvt(const float* __restrict__ src, bf16* __restrict__ dst, int R, int C) {
  __shared__ float tile[32][33];
  int c0 = blockIdx.x * 32, r0 = blockIdx.y * 32;
  int tx = threadIdx.x, ty = threadIdx.y;  // block (32,8)
#pragma unroll
  for (int i = 0; i < 4; ++i)
    tile[ty + i * 8][tx] = src[(size_t)(r0 + ty + i * 8) * C + c0 + tx];
  __syncthreads();
#pragma unroll
  for (int i = 0; i < 4; ++i)
    dst[(size_t)(c0 + ty + i * 8) * R + r0 + tx] = (bf16)tile[tx][ty + i * 8];
}

// v [b*T+t][ldv stride, h*DH+dh] bf16 -> vT [(b*NH+h)*DH+dh][t] bf16
__global__ void transpose_v(const bf16* __restrict__ v, int ldv, bf16* __restrict__ vT) {
  __shared__ bf16 tile[32][33];
  int t0 = blockIdx.x * 32, d0 = blockIdx.y * 32, bh = blockIdx.z;
  int b = bh >> 4, h = bh & 15;
  int tx = threadIdx.x, ty = threadIdx.y;
#pragma unroll
  for (int i = 0; i < 4; ++i)
    tile[ty + i * 8][tx] = v[(size_t)(b * TT + t0 + ty + i * 8) * ldv + h * DH + d0 + tx];
  __syncthreads();
#pragma unroll
  for (int i = 0; i < 4; ++i)
    vT[((size_t)bh * DH + d0 + ty + i * 8) * TT + t0 + tx] = tile[tx][ty + i * 8];
}

// ---------------- embedding + rope ----------------

__global__ void embed_rope(const int* __restrict__ ids, const float* __restrict__ emb,
                           float* __restrict__ xf, bf16* __restrict__ xb) {
  int bt = blockIdx.x;
  int t = bt & (TT - 1);
  int id = ids[bt];
  const float* row = emb + (size_t)id * DIM;
  for (int p = threadIdx.x; p < DIM / 2; p += 256) {
    float x1 = row[2 * p], x2 = row[2 * p + 1];
    float inv = __expf(-9.210340371976184f * (float)p * (1.0f / 512.0f));
    float ang = (float)t * inv;
    float c = cosf(ang), s = sinf(ang);
    float o1 = x1 * c - x2 * s;
    float o2 = x1 * s + x2 * c;
    size_t base = (size_t)bt * DIM + 2 * p;
    xf[base] = o1; xf[base + 1] = o2;
    xb[base] = (bf16)o1; xb[base + 1] = (bf16)o2;
  }
}

enum { EP_BF16 = 0, EP_F32 = 1, EP_F32_BIAS = 2, EP_BF16_BIAS = 3, EP_SILU_MUL = 4 };

// ---------------- GEMM A: 256x256 8-phase (T3+T4+T2+T5), 512 thr ----------------
// BK=64, 8 waves (2M x 4N), wave tile 128x64. LDS: 2dbuf x {A,B} x {kh0,kh1}
// of 256x32 (64-B rows, XOR chunk swizzle both-sides). Per phase: 4-8 ds_read
// + 1 half-tile stage (2 gld16) -> barrier -> setprio -> 16 MFMA -> setprio
// -> [vmcnt(4) at phases 1,3] -> barrier.  Hazard ledger: a slot staged in
// phase p is consumed 4 phases later and overwritten >=7 phases later; each
// wave's counted vmcnt precedes the barrier before first consumption.

#define GPHASE(KS, MH, LOADB, STG, WAITC)                                         \
  {                                                                               \
    if (LOADB) {                                                                  \
      _Pragma("unroll") for (int j = 0; j < 4; ++j)                               \
          bfr[j] = *(const bf16x8*)&SB[(KS)*8192 + (wn*64 + j*16 + r16)*32 + rchunk]; \
    }                                                                             \
    _Pragma("unroll") for (int i = 0; i < 4; ++i)                                 \
        af[i] = *(const bf16x8*)&SA[(KS)*8192 + (wm*128 + (MH)*64 + i*16 + r16)*32 + rchunk]; \
    STG;                                                                          \
    __builtin_amdgcn_s_barrier();                                                 \
    __builtin_amdgcn_sched_barrier(0);                                            \
    __builtin_amdgcn_s_setprio(1);                                                \
    _Pragma("unroll") for (int i = 0; i < 4; ++i)                                 \
        _Pragma("unroll") for (int j = 0; j < 4; ++j)                             \
            acc[(MH)*4 + i][j] = __builtin_amdgcn_mfma_f32_16x16x32_bf16(         \
                af[i], bfr[j], acc[(MH)*4 + i][j], 0, 0, 0);                      \
    __builtin_amdgcn_s_setprio(0);                                                \
    WAITC;                                                                        \
    __builtin_amdgcn_s_barrier();                                                 \
    __builtin_amdgcn_sched_barrier(0);                                            \
  }

template <int EP>
__global__ __launch_bounds__(512, 1) void gemm8(
    const bf16* __restrict__ A, const bf16* __restrict__ Bt, void* __restrict__ Cp,
    const float* __restrict__ bias, const bf16* __restrict__ aux,
    int M, int N, int K) {
  constexpr int BK = 64;
  __shared__ bf16 Ssh[2 * 2 * 2 * 256 * 32];  // [buf][op][kh][256*32] = 128 KiB

  const int tid = threadIdx.x;
  const int lane = tid & 63;
  const int r16 = lane & 15, hi = lane >> 4;
  const int wave = tid >> 6;
  const int wm = wave >> 2, wn = wave & 3;

  // bijective XCD swizzle (m204)
  const int nwg = gridDim.x;
  const int orig = blockIdx.x;
  const int qq = nwg >> 3, rr = nwg & 7;
  const int xcd = orig & 7, cidx = orig >> 3;
  const int wg = (xcd < rr ? xcd * (qq + 1) : rr * (qq + 1) + (xcd - rr) * qq) + cidx;
  const int gM = M / 256;
  const int m0 = (wg % gM) * 256;
  const int n0 = (wg / gM) * 256;

  const int srow = tid >> 2;               // 0..127
  const int ccol = tid & 3;
  const int skey = (srow >> 1) & 3;
  const int gcol = (ccol ^ skey) * 8;      // pre-swizzled global col
  const bf16* aS = A + (size_t)(m0 + srow) * K + gcol;
  const bf16* bS = Bt + (size_t)(n0 + srow) * K + gcol;
  const int dst0 = srow * 32 + ccol * 8;   // linear LDS dest (== tid*8 elems)

  const int rkey = (r16 >> 1) & 3;
  const int rchunk = (hi ^ rkey) * 8;

  f32x4 acc[8][4] = {};
  const int NT = K / BK;

  // prologue: stage tile 0 (order: A-kh0, B-kh0, A-kh1, B-kh1)
  {
    bf16* S0A = Ssh;
    bf16* S0B = Ssh + 16384;
    gld16(aS, S0A + dst0);
    gld16(aS + (size_t)128 * K, S0A + 4096 + dst0);
    gld16(bS, S0B + dst0);
    gld16(bS + (size_t)128 * K, S0B + 4096 + dst0);
    gld16(aS + 32, S0A + 8192 + dst0);
    gld16(aS + 32 + (size_t)128 * K, S0A + 8192 + 4096 + dst0);
    gld16(bS + 32, S0B + 8192 + dst0);
    gld16(bS + 32 + (size_t)128 * K, S0B + 8192 + 4096 + dst0);
    asm volatile("s_waitcnt vmcnt(4)" ::: "memory");
    __builtin_amdgcn_s_barrier();
    __builtin_amdgcn_sched_barrier(0);
  }

  for (int t = 0; t < NT; ++t) {
    const int cb = t & 1, nb = cb ^ 1;
    const bool pre = (t + 1) < NT;
    const size_t koff = (size_t)(t + 1) * BK;
    bf16* SA = Ssh + cb * 32768;
    bf16* SB = SA + 16384;
    bf16* NA = Ssh + nb * 32768;
    bf16* NB = NA + 16384;
    bf16x8 af[4], bfr[4];

    // p0: (ks0, mh0), stage A-kh0(t+1)
    GPHASE(0, 0, true,
      { if (pre) { gld16(aS + koff, NA + dst0);
                   gld16(aS + koff + (size_t)128 * K, NA + 4096 + dst0); } },
      {});
    // p1: (ks0, mh1), stage B-kh0(t+1), vmcnt
    GPHASE(0, 1, false,
      { if (pre) { gld16(bS + koff, NB + dst0);
                   gld16(bS + koff + (size_t)128 * K, NB + 4096 + dst0); } },
      { if (pre) asm volatile("s_waitcnt vmcnt(4)" ::: "memory");
        else     asm volatile("s_waitcnt vmcnt(0)" ::: "memory"); });
    // p2: (ks1, mh0), stage A-kh1(t+1)
    GPHASE(1, 0, true,
      { if (pre) { gld16(aS + koff + 32, NA + 8192 + dst0);
                   gld16(aS + koff + 32 + (size_t)128 * K, NA + 8192 + 4096 + dst0); } },
      {});
    // p3: (ks1, mh1), stage B-kh1(t+1), vmcnt
    GPHASE(1, 1, false,
      { if (pre) { gld16(bS + koff + 32, NB + 8192 + dst0);
                   gld16(bS + koff + 32 + (size_t)128 * K, NB + 8192 + 4096 + dst0); } },
      { if (pre) asm volatile("s_waitcnt vmcnt(4)" ::: "memory"); });
  }

#pragma unroll
  for (int mi = 0; mi < 8; ++mi) {
    const int m = m0 + wm * 128 + mi * 16 + hi * 4;
#pragma unroll
    for (int j = 0; j < 4; ++j) {
      const int n = n0 + wn * 64 + j * 16 + r16;
#pragma unroll
      for (int q = 0; q < 4; ++q) {
        size_t idx = (size_t)(m + q) * N + n;
        float v = acc[mi][j][q];
        if constexpr (EP == EP_F32) {
          ((float*)Cp)[idx] = v;
        } else if constexpr (EP == EP_F32_BIAS) {
          ((float*)Cp)[idx] = v + bias[n];
        } else if constexpr (EP == EP_BF16) {
          ((bf16*)Cp)[idx] = (bf16)v;
        } else if constexpr (EP == EP_BF16_BIAS) {
          ((bf16*)Cp)[idx] = (bf16)(v + bias[n]);
        } else {
          float sg = v / (1.0f + __expf(-v));
          ((bf16*)Cp)[idx] = (bf16)(sg * (float)aux[idx]);
        }
      }
    }
  }
}

// ---------------- GEMM B: 128x128 ring (for N=1024 shapes) ----------------

template <int BM, int BN, int WMW, int WNW, int EP>
__global__ __launch_bounds__(WMW * WNW * 64, 2) void gemmk(
    const bf16* __restrict__ A, const bf16* __restrict__ Bt, void* __restrict__ Cp,
    const float* __restrict__ bias, const bf16* __restrict__ aux,
    int M, int N, int K) {
  constexpr int BK = 32;
  constexpr int NWAVE = WMW * WNW;
  constexpr int NTHR = NWAVE * 64;
  constexpr int MF = BM / (WMW * 16);
  constexpr int NF = BN / (WNW * 16);
  constexpr int AE = BM * BK;
  constexpr int BE = BN * BK;
  constexpr int RHALF = NTHR / 4;
  __shared__ bf16 sA[4][AE];
  __shared__ bf16 sB[4][BE];

  const int tid = threadIdx.x;
  const int lane = tid & 63;
  const int r16 = lane & 15, hi = lane >> 4;
  const int wave = tid >> 6;
  const int wm = wave / WNW, wn = wave % WNW;

  const int nwg = gridDim.x;
  const int orig = blockIdx.x;
  const int qq = nwg >> 3, rr = nwg & 7;
  const int xcd = orig & 7, cidx = orig >> 3;
  const int wg = (xcd < rr ? xcd * (qq + 1) : rr * (qq + 1) + (xcd - rr) * qq) + cidx;
  const int gM = M / BM;
  const int m0 = (wg % gM) * BM;
  const int n0 = (wg / gM) * BN;

  const int srow = tid >> 2;
  const int ccol = tid & 3;
  const int skey = (srow >> 1) & 3;
  const int gcol = ((ccol ^ skey)) * 8;
  const bf16* aS = A + (size_t)(m0 + srow) * K + gcol;
  const bf16* bS = Bt + (size_t)(n0 + srow) * K + gcol;
  const int dst0 = srow * BK + ccol * 8;

  const int rkey = (r16 >> 1) & 3;
  const int rchunk = (hi ^ rkey) * 8;

  f32x4 acc[MF][NF] = {};
  const int NT = K / BK;

  gld16(aS, &sA[0][dst0]);
  gld16(aS + (size_t)RHALF * K, &sA[0][dst0 + RHALF * BK]);
  gld16(bS, &sB[0][dst0]);
  gld16(bS + (size_t)RHALF * K, &sB[0][dst0 + RHALF * BK]);
  gld16(aS + BK, &sA[1][dst0]);
  gld16(aS + BK + (size_t)RHALF * K, &sA[1][dst0 + RHALF * BK]);
  gld16(bS + BK, &sB[1][dst0]);
  gld16(bS + BK + (size_t)RHALF * K, &sB[1][dst0 + RHALF * BK]);

  for (int t = 0; t < NT; ++t) {
    const int cb = t & 3;
    const int pb = (t + 2) & 3;
    const bool pre = (t + 2) < NT;
    if (pre) {
      gld16(aS + (size_t)(t + 2) * BK, &sA[pb][dst0]);
      gld16(aS + (size_t)(t + 2) * BK + (size_t)RHALF * K, &sA[pb][dst0 + RHALF * BK]);
    }
    if (pre)             asm volatile("s_waitcnt vmcnt(6)" ::: "memory");
    else if (t + 1 < NT) asm volatile("s_waitcnt vmcnt(4)" ::: "memory");
    else                 asm volatile("s_waitcnt vmcnt(0)" ::: "memory");
    __builtin_amdgcn_s_barrier();
    __builtin_amdgcn_sched_barrier(0);

    bf16x8 bf_[NF];
#pragma unroll
    for (int j = 0; j < NF; ++j)
      bf_[j] = *(const bf16x8*)&sB[cb][(wn * (NF * 16) + j * 16 + r16) * BK + rchunk];
    if (pre) {
      gld16(bS + (size_t)(t + 2) * BK, &sB[pb][dst0]);
      gld16(bS + (size_t)(t + 2) * BK + (size_t)RHALF * K, &sB[pb][dst0 + RHALF * BK]);
    }
    bf16x8 af[MF];
#pragma unroll
    for (int i = 0; i < MF; ++i)
      af[i] = *(const bf16x8*)&sA[cb][(wm * (MF * 16) + i * 16 + r16) * BK + rchunk];
    __builtin_amdgcn_s_setprio(1);
#pragma unroll
    for (int i = 0; i < MF; ++i)
#pragma unroll
      for (int j = 0; j < NF; ++j)
        acc[i][j] = __builtin_amdgcn_mfma_f32_16x16x32_bf16(af[i], bf_[j], acc[i][j], 0, 0, 0);
    __builtin_amdgcn_s_setprio(0);
  }

#pragma unroll
  for (int i = 0; i < MF; ++i) {
    const int m = m0 + wm * (MF * 16) + i * 16 + hi * 4;
#pragma unroll
    for (int j = 0; j < NF; ++j) {
      const int n = n0 + wn * (NF * 16) + j * 16 + r16;
#pragma unroll
      for (int q = 0; q < 4; ++q) {
        size_t idx = (size_t)(m + q) * N + n;
        float v = acc[i][j][q];
        if constexpr (EP == EP_F32) {
          ((float*)Cp)[idx] = v;
        } else if constexpr (EP == EP_F32_BIAS) {
          ((float*)Cp)[idx] = v + bias[n];
        } else if constexpr (EP == EP_BF16) {
          ((bf16*)Cp)[idx] = (bf16)v;
        } else if constexpr (EP == EP_BF16_BIAS) {
          ((bf16*)Cp)[idx] = (bf16)(v + bias[n]);
        } else {
          float sg = v / (1.0f + __expf(-v));
          ((bf16*)Cp)[idx] = (bf16)(sg * (float)aux[idx]);
        }
      }
    }
  }
}

// ---------------- flash attention (non-causal) ----------------

__global__ __launch_bounds__(256, 2) void attn_flash(
    const bf16* __restrict__ Qp, const bf16* __restrict__ Kp, int ldk,
    const bf16* __restrict__ Vt, bf16* __restrict__ Op) {
  __shared__ bf16 Ks[2][128 * 32];      // [dh-half][row 0..127][32]
  __shared__ bf16 Vs[4][64 * 32];       // [t-chunk][d 0..63][32]
  __shared__ bf16 Ps[4][4][16 * 40];    // [wave][t-chunk][qrow 0..15][pad 40]
  const int tid = threadIdx.x, lane = tid & 63, wave = tid >> 6;
  const int h = blockIdx.y, b = blockIdx.z;
  const int r16 = lane & 15, hi = lane >> 4;
  const int qrow = blockIdx.x * 64 + wave * 16 + r16;

  bf16x8 qa[2];
  {
    const bf16* qp = Qp + (size_t)(b * TT + qrow) * ldk + h * DH + hi * 8;
    qa[0] = *(const bf16x8*)qp;
    qa[1] = *(const bf16x8*)(qp + 32);
  }
  const bf16* kBase = Kp + (size_t)(b * TT) * ldk + h * DH;
  const bf16* vBase = Vt + (size_t)(b * NH + h) * DH * TT;

  const int srow = tid >> 2, ccol = tid & 3;
  const int skey = (srow >> 1) & 3;
  const int scolS = (ccol ^ skey) * 8;
  const int dstc = ccol * 8;
  const int rkey = (r16 >> 1) & 3;
  const int rchunk = (hi ^ rkey) * 8;

  float m_run[4] = {-1e30f, -1e30f, -1e30f, -1e30f};
  float l_run[4] = {0.f, 0.f, 0.f, 0.f};
  f32x4 oacc[4] = {};

  for (int kt = 0; kt < TT; kt += 128) {
#pragma unroll
    for (int half = 0; half < 2; ++half) {
      gld16(kBase + (size_t)(kt + srow) * ldk + half * 32 + scolS, &Ks[half][srow * 32 + dstc]);
      gld16(kBase + (size_t)(kt + 64 + srow) * ldk + half * 32 + scolS, &Ks[half][(64 + srow) * 32 + dstc]);
    }
#pragma unroll
    for (int ks = 0; ks < 4; ++ks)
      gld16(vBase + (size_t)srow * TT + kt + ks * 32 + scolS, &Vs[ks][srow * 32 + dstc]);
    __syncthreads();

    f32x4 s[8];
#pragma unroll
    for (int kg = 0; kg < 8; ++kg) {
      f32x4 z = {};
      bf16x8 kb0 = *(const bf16x8*)&Ks[0][(kg * 16 + r16) * 32 + rchunk];
      bf16x8 kb1 = *(const bf16x8*)&Ks[1][(kg * 16 + r16) * 32 + rchunk];
      z = __builtin_amdgcn_mfma_f32_16x16x32_bf16(qa[0], kb0, z, 0, 0, 0);
      z = __builtin_amdgcn_mfma_f32_16x16x32_bf16(qa[1], kb1, z, 0, 0, 0);
      s[kg] = z * 0.125f;  // DH^-0.5
    }
#pragma unroll
    for (int i = 0; i < 4; ++i) {
      float pm = s[0][i];
#pragma unroll
      for (int kg = 1; kg < 8; ++kg) pm = fmaxf(pm, s[kg][i]);
      pm = fmaxf(pm, __shfl_xor(pm, 1));
      pm = fmaxf(pm, __shfl_xor(pm, 2));
      pm = fmaxf(pm, __shfl_xor(pm, 4));
      pm = fmaxf(pm, __shfl_xor(pm, 8));
      float mnew = fmaxf(m_run[i], pm);
      float sc = __expf(m_run[i] - mnew);
      m_run[i] = mnew;
      l_run[i] *= sc;
#pragma unroll
      for (int n = 0; n < 4; ++n) oacc[n][i] *= sc;
#pragma unroll
      for (int kg = 0; kg < 8; ++kg) {
        float p = __expf(s[kg][i] - mnew);
        l_run[i] += p;
        Ps[wave][kg >> 1][(hi * 4 + i) * 40 + (kg & 1) * 16 + r16] = (bf16)p;
      }
    }
#pragma unroll
    for (int ks = 0; ks < 4; ++ks) {
      bf16x8 pa = *(const bf16x8*)&Ps[wave][ks][r16 * 40 + hi * 8];
#pragma unroll
      for (int n = 0; n < 4; ++n) {
        bf16x8 vb = *(const bf16x8*)&Vs[ks][(n * 16 + r16) * 32 + rchunk];
        oacc[n] = __builtin_amdgcn_mfma_f32_16x16x32_bf16(pa, vb, oacc[n], 0, 0, 0);
      }
    }
    __syncthreads();
  }

#pragma unroll
  for (int i = 0; i < 4; ++i) {
    float l = l_run[i];
    l += __shfl_xor(l, 1);
    l += __shfl_xor(l, 2);
    l += __shfl_xor(l, 4);
    l += __shfl_xor(l, 8);
    float inv = 1.0f / l;
    int trow = blockIdx.x * 64 + wave * 16 + hi * 4 + i;
    size_t base = ((size_t)b * TT + trow) * DIM + h * DH;
#pragma unroll
    for (int n = 0; n < 4; ++n)
      Op[base + n * 16 + r16] = (bf16)(oacc[n][i] * inv);
  }
}

// ---------------- residual + rmsnorm ----------------

__global__ __launch_bounds__(256) void resid_rms(
    const float* __restrict__ xin, const float* __restrict__ y, const float* __restrict__ wgt,
    float* __restrict__ xf_out, bf16* __restrict__ xb_out) {
  __shared__ float red[4];
  const int r = blockIdx.x, tid = threadIdx.x;
  const size_t base = (size_t)r * DIM + tid * 4;
  float4 v = *(const float4*)(xin + base);
  float4 u = *(const float4*)(y + base);
  v.x += u.x; v.y += u.y; v.z += u.z; v.w += u.w;
  float ss = v.x * v.x + v.y * v.y + v.z * v.z + v.w * v.w;
#pragma unroll
  for (int d = 1; d < 64; d <<= 1) ss += __shfl_xor(ss, d);
  if ((tid & 63) == 0) red[tid >> 6] = ss;
  __syncthreads();
  ss = red[0] + red[1] + red[2] + red[3];
  float sc = rsqrtf(ss * (1.0f / DIM) + 1e-8f);
  const float4 wv = *(const float4*)(wgt + tid * 4);
  float o0 = v.x * sc * wv.x, o1 = v.y * sc * wv.y, o2 = v.z * sc * wv.z, o3 = v.w * sc * wv.w;
  if (xf_out) {
    float4 ov = {o0, o1, o2, o3};
    *(float4*)(xf_out + base) = ov;
  }
  bf16x4 ob = {(bf16)o0, (bf16)o1, (bf16)o2, (bf16)o3};
  *(bf16x4*)(xb_out + base) = ob;
}

// ---------------- slot softmax rows (scale D^-0.5 = 1/32) ----------------

__global__ __launch_bounds__(256) void softmax_rows(const float* __restrict__ Sc, bf16* __restrict__ P) {
  __shared__ float red[4];
  const int r = blockIdx.x, tid = threadIdx.x;
  const float* row = Sc + (size_t)r * NSLOT;
  float4 v[4];
#pragma unroll
  for (int i = 0; i < 4; ++i) v[i] = *(const float4*)(row + tid * 4 + i * 1024);
  float mx = -1e30f;
#pragma unroll
  for (int i = 0; i < 4; ++i)
    mx = fmaxf(fmaxf(fmaxf(fmaxf(mx, v[i].x), v[i].y), v[i].z), v[i].w);
#pragma unroll
  for (int d = 1; d < 64; d <<= 1) mx = fmaxf(mx, __shfl_xor(mx, d));
  if ((tid & 63) == 0) red[tid >> 6] = mx;
  __syncthreads();
  mx = fmaxf(fmaxf(red[0], red[1]), fmaxf(red[2], red[3]));
  __syncthreads();
  float e[16];
  float sum = 0.f;
#pragma unroll
  for (int i = 0; i < 4; ++i) {
    e[i * 4 + 0] = __expf((v[i].x - mx) * 0.03125f);
    e[i * 4 + 1] = __expf((v[i].y - mx) * 0.03125f);
    e[i * 4 + 2] = __expf((v[i].z - mx) * 0.03125f);
    e[i * 4 + 3] = __expf((v[i].w - mx) * 0.03125f);
    sum += e[i * 4 + 0] + e[i * 4 + 1] + e[i * 4 + 2] + e[i * 4 + 3];
  }
#pragma unroll
  for (int d = 1; d < 64; d <<= 1) sum += __shfl_xor(sum, d);
  if ((tid & 63) == 0) red[tid >> 6] = sum;
  __syncthreads();
  sum = red[0] + red[1] + red[2] + red[3];
  float inv = 1.0f / sum;
#pragma unroll
  for (int i = 0; i < 4; ++i) {
    bf16x4 ob = {(bf16)(e[i * 4 + 0] * inv), (bf16)(e[i * 4 + 1] * inv),
                 (bf16)(e[i * 4 + 2] * inv), (bf16)(e[i * 4 + 3] * inv)};
    *(bf16x4*)(P + (size_t)r * NSLOT + tid * 4 + i * 1024) = ob;
  }
}

// ---------------- host orchestration ----------------

extern "C" void kernel_launch(void* const* d_in, const int* in_sizes, int n_in,
                              void* d_out, int out_size, void* d_ws, size_t ws_size,
                              hipStream_t stream) {
  (void)in_sizes; (void)n_in; (void)out_size;
  const int* ids = (const int*)d_in[0];
  const float* emb = (const float*)d_in[1];
  const float* Wq = (const float*)d_in[2];
  const float* Wk = (const float*)d_in[3];
  const float* Wv = (const float*)d_in[4];
  const float* Wo = (const float*)d_in[5];
  const float* bo = (const float*)d_in[6];
  const float* n1 = (const float*)d_in[7];
  const float* Wg = (const float*)d_in[8];
  const float* Wu = (const float*)d_in[9];
  const float* Wd = (const float*)d_in[10];
  const float* n2 = (const float*)d_in[11];
  const float* memp = (const float*)d_in[12];
  const float* Wsp = (const float*)d_in[13];
  const float* bsp = (const float*)d_in[14];
  const float* Wrp = (const float*)d_in[15];
  const float* brp = (const float*)d_in[16];
  const float* nout = (const float*)d_in[17];

  char* w = (char*)d_ws;
  auto alloc = [&](size_t bytes) -> void* {
    void* p = (void*)w;
    w += (bytes + 255) & ~(size_t)255;
    return p;
  };

  const size_t dd = (size_t)DIM * DIM;
  const size_t dff = (size_t)DIM * FFD;

  bf16* tok_b = (bf16*)alloc((size_t)NV * DIM * 2);
  bf16* mem_b = (bf16*)alloc((size_t)NSLOT * DIM * 2);
  bf16* memT  = (bf16*)alloc((size_t)NSLOT * DIM * 2);
  bf16* WspT  = (bf16*)alloc(dd * 2);
  bf16* WrpT  = (bf16*)alloc(dd * 2);
  float* xf   = (float*)alloc((size_t)BT * DIM * 4);
  bf16* xb    = (bf16*)alloc((size_t)BT * DIM * 2);
  float* yb   = (float*)alloc((size_t)BT * DIM * 4);
  bf16* W3T   = (bf16*)alloc(3 * dd * 2);   // [WqT | WkT | WvT] rows
  bf16* WoT   = (bf16*)alloc(dd * 2);
  bf16* WgT   = (bf16*)alloc(dff * 2);
  bf16* WuT   = (bf16*)alloc(dff * 2);
  bf16* WdT   = (bf16*)alloc(dff * 2);
  bf16* qkv   = (bf16*)alloc((size_t)BT * 3 * DIM * 2);
  bf16* vT_   = (bf16*)alloc((size_t)BT * DIM * 2);
  bf16* ot_   = (bf16*)alloc((size_t)BT * DIM * 2);
  bf16* qb    = (bf16*)alloc((size_t)BT * DIM * 2);
  bf16* rb    = (bf16*)alloc((size_t)BT * DIM * 2);
  bf16* hb    = (bf16*)alloc((size_t)BT * DIM * 2);

  size_t used = (size_t)(w - (char*)d_ws);
  size_t region_bytes = (size_t)BT * NSLOT * 4 + (size_t)BT * NSLOT * 2;
  char* region;
  if (used + region_bytes <= ws_size) region = (char*)alloc(region_bytes);
  else region = (char*)d_out;
  bf16* Ub = (bf16*)region;
  bf16* Hb = (bf16*)(region + (size_t)BT * FFD * 2);
  float* scoresF = (float*)region;
  bf16* attnb = (bf16*)(region + (size_t)BT * NSLOT * 4);

  dim3 blkT(32, 8);

  cvt_bf16<<<NV * DIM / 1024, 256, 0, stream>>>(emb, tok_b, (long)NV * DIM);
  cvt_bf16<<<NSLOT * DIM / 1024, 256, 0, stream>>>(memp, mem_b, (long)NSLOT * DIM);
  transpose_cvt<<<dim3(DIM / 32, NSLOT / 32), blkT, 0, stream>>>(memp, memT, NSLOT, DIM);
  transpose_cvt<<<dim3(DIM / 32, DIM / 32), blkT, 0, stream>>>(Wsp, WspT, DIM, DIM);
  transpose_cvt<<<dim3(DIM / 32, DIM / 32), blkT, 0, stream>>>(Wrp, WrpT, DIM, DIM);
  embed_rope<<<BT, 256, 0, stream>>>(ids, emb, xf, xb);

  for (int l = 0; l < NL; ++l) {
    transpose_cvt<<<dim3(32, 32), blkT, 0, stream>>>(Wq + l * dd, W3T, DIM, DIM);
    transpose_cvt<<<dim3(32, 32), blkT, 0, stream>>>(Wk + l * dd, W3T + dd, DIM, DIM);
    transpose_cvt<<<dim3(32, 32), blkT, 0, stream>>>(Wv + l * dd, W3T + 2 * dd, DIM, DIM);
    transpose_cvt<<<dim3(32, 32), blkT, 0, stream>>>(Wo + l * dd, WoT, DIM, DIM);
    transpose_cvt<<<dim3(FFD / 32, DIM / 32), blkT, 0, stream>>>(Wg + l * dff, WgT, DIM, FFD);
    transpose_cvt<<<dim3(FFD / 32, DIM / 32), blkT, 0, stream>>>(Wu + l * dff, WuT, DIM, FFD);
    transpose_cvt<<<dim3(DIM / 32, FFD / 32), blkT, 0, stream>>>(Wd + l * dff, WdT, FFD, DIM);

    gemm8<EP_BF16><<<dim3(16 * 12), 512, 0, stream>>>(
        xb, W3T, qkv, nullptr, nullptr, BT, 3 * DIM, DIM);
    transpose_v<<<dim3(TT / 32, DH / 32, BB * NH), blkT, 0, stream>>>(qkv + 2 * DIM, 3 * DIM, vT_);
    attn_flash<<<dim3(TT / 64, NH, BB), 256, 0, stream>>>(qkv, qkv + DIM, 3 * DIM, vT_, ot_);
    gemmk<128, 128, 2, 2, EP_F32_BIAS><<<dim3(8 * 32), 256, 0, stream>>>(
        ot_, WoT, yb, bo + l * DIM, nullptr, BT, DIM, DIM);
    resid_rms<<<BT, 256, 0, stream>>>(xf, yb, n1 + l * DIM, xf, xb);
    gemm8<EP_BF16><<<dim3(16 * 16), 512, 0, stream>>>(
        xb, WuT, Ub, nullptr, nullptr, BT, FFD, DIM);
    gemm8<EP_SILU_MUL><<<dim3(16 * 16), 512, 0, stream>>>(
        xb, WgT, Hb, nullptr, Ub, BT, FFD, DIM);
    gemmk<128, 128, 2, 2, EP_F32><<<dim3(8 * 32), 256, 0, stream>>>(
        Hb, WdT, yb, nullptr, nullptr, BT, DIM, FFD);
    resid_rms<<<BT, 256, 0, stream>>>(xf, yb, n2 + l * DIM, xf, xb);
  }

  gemmk<128, 128, 2, 2, EP_BF16_BIAS><<<dim3(8 * 32), 256, 0, stream>>>(
      xb, WspT, qb, bsp, nullptr, BT, DIM, DIM);
  gemm8<EP_F32><<<dim3(16 * 16), 512, 0, stream>>>(
      qb, mem_b, scoresF, nullptr, nullptr, BT, NSLOT, DIM);
  softmax_rows<<<BT, 256, 0, stream>>>(scoresF, attnb);
  gemmk<128, 128, 2, 2, EP_BF16><<<dim3(8 * 32), 256, 0, stream>>>(
      attnb, memT, rb, nullptr, nullptr, BT, DIM, NSLOT);
  gemmk<128, 128, 2, 2, EP_F32_BIAS><<<dim3(8 * 32), 256, 0, stream>>>(
      rb, WrpT, yb, brp, nullptr, BT, DIM, DIM);
  resid_rms<<<BT, 256, 0, stream>>>(xf, yb, nout, nullptr, hb);
  gemm8<EP_F32><<<dim3(16 * 125), 512, 0, stream>>>(
      hb, tok_b, (float*)d_out, nullptr, nullptr, BT, NV, DIM);
}